// Round 12
// baseline (169.475 us; speedup 1.0000x reference)
//
#include <hip/hip_runtime.h>
#include <math.h>

// Problem constants
#define NN 256
#define KK 512
#define JJ 6
#define BB 8
#define MPTS 100000
#define NBINS (KK * KK)
// K/(2*pi)
#define KF_SCALE 81.48733086305615f

typedef _Float16 h8 __attribute__((ext_vector_type(8)));

// ---------- device helpers ----------

// Abramowitz & Stegun 9.8.1 / 9.8.2 modified Bessel I0, float
__device__ __forceinline__ float i0f_dev(float x) {
    float ax = fabsf(x);
    if (ax < 3.75f) {
        float t = x / 3.75f; t *= t;
        return 1.0f + t*(3.5156229f + t*(3.0899424f + t*(1.2067492f +
               t*(0.2659732f + t*(0.0360768f + t*0.0045813f)))));
    } else {
        float t = 3.75f / ax;
        return (expf(ax) * rsqrtf(ax)) *
               (0.39894228f + t*(0.01328592f + t*(0.00225319f + t*(-0.00157565f +
                t*(0.00916281f + t*(-0.02057706f + t*(0.02635537f +
                t*(-0.01647633f + t*0.00392377f))))))));
    }
}

__device__ __forceinline__ float kbf(float t, float beta, float inv_i0b) {
    float u = t * (1.0f / 3.0f);       // 2*t/J, J=6
    float q = fmaxf(1.0f - u * u, 0.0f);
    return i0f_dev(beta * sqrtf(q)) * inv_i0b;
}

// order-preserving float<->uint for atomic min/max
__device__ __forceinline__ unsigned fkey(float f) {
    unsigned u = __float_as_uint(f);
    return (u & 0x80000000u) ? ~u : (u | 0x80000000u);
}
__device__ __forceinline__ float funkey(unsigned k) {
    unsigned u = (k & 0x80000000u) ? (k & 0x7FFFFFFFu) : ~k;
    return __uint_as_float(u);
}

// inclusive wave scan (64 lanes)
__device__ __forceinline__ int wave_scan(int x, int lane) {
#pragma unroll
    for (int off = 1; off < 64; off <<= 1) {
        int y = __shfl_up(x, off, 64);
        if (lane >= off) x += y;
    }
    return x;
}

// KB weight via 1024-entry LUT over t in [-3,3], linear interp (err ~4e-4)
__device__ __forceinline__ float kb_lut(const float* __restrict__ sT, float t) {
    float u = (t + 3.0f) * (1023.0f / 6.0f);   // t in (-3, 3] -> u in (0, 1023]
    int i = (int)u;
    i = min(i, 1022);
    float f = u - (float)i;
    float a = sT[i];
    return a + f * (sT[i + 1] - sT[i]);
}

// ---------- binning kernels ----------

// count_bins also: inits min/max cells, builds the KB LUT (threads 0..1023).
__global__ __launch_bounds__(256) void count_bins(
    const float2* __restrict__ uv2, int* __restrict__ counts,
    unsigned* __restrict__ mmin, unsigned* __restrict__ mmax,
    float* __restrict__ lut, float beta, float inv_i0b)
{
    int m = blockIdx.x * 256 + threadIdx.x;
    if (m < 8) mmin[m] = 0xFFFFFFFFu;
    else if (m < 16) mmax[m - 8] = 0u;
    if (m < 1024) {
        float t = -3.0f + (6.0f / 1023.0f) * (float)m;
        lut[m] = kbf(t, beta, inv_i0b);
    }
    if (m >= MPTS) return;
    float2 u = uv2[m];
    int b0 = (int)floorf(u.x * KF_SCALE) & (KK - 1);
    int b1 = (int)floorf(u.y * KF_SCALE) & (KK - 1);
    atomicAdd(&counts[(b0 << 9) | b1], 1);
}

// Single-pass decoupled-lookback exclusive scan of counts[262144] -> offsets.
__global__ __launch_bounds__(1024) void scan_k(
    const int* __restrict__ counts, int* __restrict__ offsets,
    unsigned long long* __restrict__ desc)
{
    __shared__ int part[16];
    __shared__ int s_prefix;
    int tid = threadIdx.x;
    int lane = tid & 63;
    int w = tid >> 6;                       // [0,16)
    int g = blockIdx.x * 1024 + tid;

    int v = counts[g];
    int x = wave_scan(v, lane);
    if (lane == 63) part[w] = x;
    __syncthreads();
    if (tid < 16) {
        int p = part[tid];
#pragma unroll
        for (int off = 1; off < 16; off <<= 1) {
            int y = __shfl_up(p, off, 64);
            if (tid >= off) p += y;
        }
        part[tid] = p;
    }
    __syncthreads();
    int incl = x + ((w > 0) ? part[w - 1] : 0);
    int total = part[15];                   // block aggregate

    if (tid == 0) {
        unsigned long long pack = ((unsigned long long)(unsigned)total << 2) |
                                  ((blockIdx.x == 0) ? 2ULL : 1ULL);
        atomicExch(&desc[blockIdx.x], pack);
        if (blockIdx.x == 0) s_prefix = 0;
    }

    if (blockIdx.x > 0 && w == 0) {
        int prefix = 0;
        int base = blockIdx.x - 1;
        bool done = false;
        while (!done) {
            int idx = base - lane;          // lane 0 = nearest predecessor
            unsigned long long d = 0;
            if (idx >= 0) {
                do { d = atomicAdd(&desc[idx], 0ULL); } while ((d & 3ULL) == 0ULL);
            }
            unsigned long long mask = __ballot(idx >= 0 && (d & 3ULL) == 2ULL);
            int f = (mask != 0ULL) ? (__ffsll((long long)mask) - 1) : 64;
            int contrib = (idx >= 0 && lane <= f) ? (int)(d >> 2) : 0;
#pragma unroll
            for (int off = 1; off < 64; off <<= 1)
                contrib += __shfl_xor(contrib, off, 64);
            prefix += contrib;
            base -= 64;
            done = (mask != 0ULL);
        }
        if (lane == 0) {
            s_prefix = prefix;
            atomicExch(&desc[blockIdx.x],
                       ((unsigned long long)(unsigned)(prefix + total) << 2) | 2ULL);
        }
    }
    __syncthreads();

    offsets[g] = incl - v + s_prefix;
    if (g == 0) offsets[NBINS] = MPTS;
}

// fill_records: 64B record per point, written to its CSR slot (sorted by bin):
//  [0,12)  w0[6]  f16 axis-0 KB weights
//  [12,24) w1[6]  f16 axis-1 KB weights
//  [24,28) bin1   int (c1 coordinate of the point's bin)
//  [28,32) pad
//  [32,64) y      16 x f16: 8 batches, (re,im) pairs, pre-weighted
// Weights via LDS copy of the 1024-entry LUT (no divergent i0f).
__global__ __launch_bounds__(256) void fill_records(
    const float2* __restrict__ uv2,
    const float* __restrict__ y_real, const float* __restrict__ y_imag,
    const float* __restrict__ weights, const int* __restrict__ offsets,
    int* __restrict__ counts, char* __restrict__ rec,
    const float* __restrict__ lut)
{
    __shared__ float sT[1024];
    int tid = threadIdx.x;
#pragma unroll
    for (int q = 0; q < 4; ++q) sT[q * 256 + tid] = lut[q * 256 + tid];
    __syncthreads();

    int m = blockIdx.x * 256 + tid;
    if (m >= MPTS) return;
    float2 u = uv2[m];
    float kf0 = u.x * KF_SCALE;
    float kf1 = u.y * KF_SCALE;
    float f0 = floorf(kf0), f1 = floorf(kf1);
    float fr0 = kf0 - f0, fr1 = kf1 - f1;
    int b1c = (int)f1 & (KK - 1);
    int bin = (((int)f0 & (KK - 1)) << 9) | b1c;
    int old = atomicSub(&counts[bin], 1);
    int slot = offsets[bin] + old - 1;

    _Float16 hw[12];
#pragma unroll
    for (int j = 0; j < JJ; ++j) {
        hw[j]     = (_Float16)kb_lut(sT, (float)(j - 2) - fr0);
        hw[6 + j] = (_Float16)kb_lut(sT, (float)(j - 2) - fr1);
    }

    float4 c0v, c1v;
    _Float16* p0 = (_Float16*)&c0v;
    _Float16* p1 = (_Float16*)&c1v;
#pragma unroll
    for (int j = 0; j < 8; ++j) p0[j] = hw[j];        // w0[0..5], w1[0..1]
#pragma unroll
    for (int j = 0; j < 4; ++j) p1[j] = hw[8 + j];    // w1[2..5]
    ((int*)&c1v)[2] = b1c;
    ((int*)&c1v)[3] = 0;

    float wm = weights[m];
    h8 ha, hb;
#pragma unroll
    for (int b = 0; b < 4; ++b) {
        ha[2 * b]     = (_Float16)(y_real[b * MPTS + m] * wm);
        ha[2 * b + 1] = (_Float16)(y_imag[b * MPTS + m] * wm);
        hb[2 * b]     = (_Float16)(y_real[(b + 4) * MPTS + m] * wm);
        hb[2 * b + 1] = (_Float16)(y_imag[(b + 4) * MPTS + m] * wm);
    }

    float4* dst = (float4*)(rec + (size_t)slot * 64);
    dst[0] = c0v;
    dst[1] = c1v;
    dst[2] = *(float4*)&ha;
    dst[3] = *(float4*)&hb;
}

// ---------- gather v6: 32 cells/wave, 2 lanes/cell, 8 waves/SIMD ----------
// Wave owns 32 cells (fixed c0, c1 = c1base + (lane&31)); lanes 0-31 accumulate
// batches 0-3, lanes 32-63 batches 4-7. Per bin-row the 37-bin span is staged
// into per-wave LDS (88B stride, <=3-way conflicts) in 32-point chunks with
// coalesced float4 loads; each lane sweeps only its own CSR sub-range.
__global__ __launch_bounds__(256) void gather_grid(
    const int* __restrict__ offsets, const char* __restrict__ rec,
    float* __restrict__ grid)
{
    __shared__ __align__(16) char lds[4][2816];   // 32 pts x 88B per wave
    int t = threadIdx.x;
    int lane = t & 63;
    int w = t >> 6;
    int half = lane >> 5;              // 0: batches 0-3, 1: batches 4-7
    int l32 = lane & 31;
    int j = blockIdx.x;                // 2048 blocks: xcd(3) | c0low(6) | q(2)
    int xcd = j & 7;
    int c0 = (xcd << 6) + ((j >> 3) & 63);
    int q4 = j >> 9;                   // [0,4)
    int c1base = (q4 << 7) + (w << 5); // [0,512) step 32
    int c1 = c1base + l32;
    int wa = c1 - 3, wb = c1 + 2;      // lane's bin window (unwrapped)

    char* myl = lds[w];

    float aR[4], aI[4];
#pragma unroll
    for (int b = 0; b < 4; ++b) { aR[b] = 0.0f; aI[b] = 0.0f; }

    for (int j0 = 0; j0 < JJ; ++j0) {
        int r0 = (c0 - (j0 - 2)) & (KK - 1);
        int rowbase = r0 << 9;
        int lo = c1base - 3, hi = c1base + 33;
        int nseg, ga0, gb0, ga1, gb1;
        if (lo < 0)        { ga0 = lo; gb0 = -1;  ga1 = 0;   gb1 = hi; nseg = 2; }
        else if (hi > 511) { ga0 = lo; gb0 = 511; ga1 = 512; gb1 = hi; nseg = 2; }
        else               { ga0 = lo; gb0 = hi;  ga1 = 0;   gb1 = 0;  nseg = 1; }

        for (int sgi = 0; sgi < nseg; ++sgi) {
            int ga = sgi ? ga1 : ga0;
            int gb = sgi ? gb1 : gb0;
            int pstart = offsets[rowbase + (ga & 511)];          // wave-uniform
            int pend   = offsets[rowbase + ((gb & 511) + 1)];    // wave-uniform
            int ia = max(wa, ga), ib = min(wb, gb);
            bool has = ia <= ib;
            int pA = has ? offsets[rowbase + (ia & 511)] : 0;
            int pB = has ? ((ib == gb) ? pend
                                       : offsets[rowbase + ((ib + 1) & 511)]) : 0;

            for (int pc = pstart; pc < pend; pc += 32) {
                int cnt = min(32, pend - pc);
                // stage chunk (coalesced): qq covers points [pc+16qq, pc+16qq+16)
                int sub = lane & 3;
                int prow = lane >> 2;      // [0,16)
#pragma unroll
                for (int qq = 0; qq < 2; ++qq) {
                    if (16 * qq < cnt) {
                        int pp = min(pc + prow + 16 * qq, MPTS - 1);
                        float4 v = *(const float4*)(rec + (size_t)pp * 64 + sub * 16);
                        *(float4*)(myl + (prow + 16 * qq) * 88 + sub * 16) = v;
                    }
                }
                // per-lane sweep of its own range within the chunk
                int pLo = max(pA, pc), pHi = min(pB, pc + cnt);
                for (int p = pLo; p < pHi; ++p) {
                    const char* rp = myl + (p - pc) * 88;
                    int bin1 = *(const int*)(rp + 24);
                    int idx = (c1 - bin1 + 2) & 511;   // wrap-exact o1+2
                    bool ok = idx <= 5;
                    idx = ok ? idx : 0;
                    float w0 = (float)*(const _Float16*)(rp + j0 * 2);
                    float w1 = (float)*(const _Float16*)(rp + 12 + idx * 2);
                    float ww = ok ? w0 * w1 : 0.0f;
                    h8 yv = *(const h8*)(rp + 32 + (half << 4));
#pragma unroll
                    for (int b = 0; b < 4; ++b) {
                        aR[b] += (float)yv[2 * b]     * ww;   // v_fma_mix
                        aI[b] += (float)yv[2 * b + 1] * ww;
                    }
                }
            }
        }
    }

    float2* g2 = (float2*)grid;
    int c = (c0 << 9) + c1;
#pragma unroll
    for (int b = 0; b < 4; ++b)
        g2[((size_t)((half << 2) + b) << 18) + c] = make_float2(aR[b], aI[b]);
}

// ---------- per-wave 512-pt FFT: 8(reg) x 64(lanes via shfl), sign +i ----------
// Twiddles from an LDS table tw[k] = (cos, sin) of +2*pi*k/512, k in [0,256).
__device__ __forceinline__ void wave_fft512(float xr[8], float xi[8], int lane,
                                            const float2* __restrict__ tw)
{
    float a0r = xr[0]+xr[4], a0i = xi[0]+xi[4];
    float a4r = xr[0]-xr[4], a4i = xi[0]-xi[4];
    float a2r = xr[2]+xr[6], a2i = xi[2]+xi[6];
    float a6r = xr[2]-xr[6], a6i = xi[2]-xi[6];
    float a1r = xr[1]+xr[5], a1i = xi[1]+xi[5];
    float a5r = xr[1]-xr[5], a5i = xi[1]-xi[5];
    float a3r = xr[3]+xr[7], a3i = xi[3]+xi[7];
    float a7r = xr[3]-xr[7], a7i = xi[3]-xi[7];
    float b0r = a0r+a2r, b0i = a0i+a2i;
    float b2r = a0r-a2r, b2i = a0i-a2i;
    float b4r = a4r-a6i, b4i = a4i+a6r;    // a4 + i*a6
    float b6r = a4r+a6i, b6i = a4i-a6r;    // a4 - i*a6
    float b1r = a1r+a3r, b1i = a1i+a3i;
    float b3r = a1r-a3r, b3i = a1i-a3i;
    float b5r = a5r-a7i, b5i = a5i+a7r;
    float b7r = a5r+a7i, b7i = a5i-a7r;
    const float S2 = 0.70710678118654752f;
    float w5r = S2*(b5r-b5i), w5i = S2*(b5r+b5i);     // W8^1 * b5
    float w7r = -S2*(b7r+b7i), w7i = S2*(b7r-b7i);    // W8^3 * b7
    float y0r = b0r+b1r, y0i = b0i+b1i;
    float y4r = b0r-b1r, y4i = b0i-b1i;
    float y1r = b4r+w5r, y1i = b4i+w5i;
    float y5r = b4r-w5r, y5i = b4i-w5i;
    float y2r = b2r-b3i, y2i = b2i+b3r;    // b2 + i*b3
    float y6r = b2r+b3i, y6i = b2i-b3r;
    float y3r = b6r+w7r, y3i = b6i+w7i;
    float y7r = b6r-w7r, y7i = b6i-w7i;

    // T[d] = Y[d] * w^(p*d), w = e^{+2pi i p/512} from table, p = brev6(lane)
    int p = __brev((unsigned)lane) >> 26;
    float2 w0v = tw[p];
    float c1 = w0v.x, s1 = w0v.y;
    float wr = c1, wi = s1, tr;
    xr[0] = y0r; xi[0] = y0i;
    xr[1] = y1r*wr - y1i*wi; xi[1] = y1i*wr + y1r*wi;
    tr = wr*c1 - wi*s1; wi = wr*s1 + wi*c1; wr = tr;
    xr[2] = y2r*wr - y2i*wi; xi[2] = y2i*wr + y2r*wi;
    tr = wr*c1 - wi*s1; wi = wr*s1 + wi*c1; wr = tr;
    xr[3] = y3r*wr - y3i*wi; xi[3] = y3i*wr + y3r*wi;
    tr = wr*c1 - wi*s1; wi = wr*s1 + wi*c1; wr = tr;
    xr[4] = y4r*wr - y4i*wi; xi[4] = y4i*wr + y4r*wi;
    tr = wr*c1 - wi*s1; wi = wr*s1 + wi*c1; wr = tr;
    xr[5] = y5r*wr - y5i*wi; xi[5] = y5i*wr + y5r*wi;
    tr = wr*c1 - wi*s1; wi = wr*s1 + wi*c1; wr = tr;
    xr[6] = y6r*wr - y6i*wi; xi[6] = y6i*wr + y6r*wi;
    tr = wr*c1 - wi*s1; wi = wr*s1 + wi*c1; wr = tr;
    xr[7] = y7r*wr - y7i*wi; xi[7] = y7i*wr + y7r*wi;

    // cross-lane FFT64 over p; stage twiddle e^{+i*pi*j/m} = tw[j << (8-t)]
#pragma unroll
    for (int t = 0; t < 6; ++t) {
        int m = 1 << t;
        int j = lane & (m - 1);
        float2 sv = tw[j << (8 - t)];
        float wc = sv.x, wsn = sv.y;
        bool hi = (lane & m) != 0;
#pragma unroll
        for (int d = 0; d < 8; ++d) {
            float pR = __shfl_xor(xr[d], m, 64);
            float pI = __shfl_xor(xi[d], m, 64);
            float bR = hi ? xr[d] : pR;
            float bI = hi ? xi[d] : pI;
            float aR = hi ? pR : xr[d];
            float aI = hi ? pI : xi[d];
            float wbR = wc * bR - wsn * bI;
            float wbI = wc * bI + wsn * bR;
            xr[d] = hi ? aR - wbR : aR + wbR;
            xi[d] = hi ? aI - wbI : aI + wbI;
        }
    }
}

// fftA: k2-transform. 512 blocks x 8 waves; wave = row (b, k1).
__global__ __launch_bounds__(512) void fftA(
    const float2* __restrict__ grid2, float2* __restrict__ C)
{
    __shared__ float sR[2112], sI[2112];   // 8 waves * 264, stride33 swizzle
    __shared__ float2 tw[256];
    int t = threadIdx.x;
    int lane = t & 63;
    int w = t >> 6;
    int b = blockIdx.x & 7;
    int k1base = (blockIdx.x >> 3) << 3;
    int k1 = k1base + w;

    if (t < 256) {
        float ang = (float)(2.0 * M_PI / 512.0) * (float)t;
        float s, c; sincosf(ang, &s, &c);
        tw[t] = make_float2(c, s);
    }

    const float2* row = grid2 + ((size_t)b << 18) + ((size_t)k1 << 9);
    int p = __brev((unsigned)lane) >> 26;
    float xr[8], xi[8];
#pragma unroll
    for (int a = 0; a < 8; ++a) {
        float2 v = row[p + (a << 6)];
        xr[a] = v.x; xi[a] = v.y;
    }
    __syncthreads();                       // table ready

    wave_fft512(xr, xi, lane, tw);

    bool act = (lane < 16) | (lane >= 48);
    int lpp = (lane < 16) ? lane : (lane - 32);   // [0,32)
    if (act) {
#pragma unroll
        for (int d = 0; d < 8; ++d) {
            int addr = w * 264 + d * 33 + lpp;    // conflict-free swizzle
            sR[addr] = xr[d];
            sI[addr] = xi[d];
        }
    }
    __syncthreads();

#pragma unroll
    for (int pp = 0; pp < 4; ++pp) {
        int idx = pp * 512 + t;                   // [0,2048) = 256 s2 x 8 k1
        int kk = idx & 7;
        int s2 = idx >> 3;
        int v = (s2 + 128) & 255;                 // v = 8*lpp + d
        int d = v & 7;
        int lp = v >> 3;
        int addr = kk * 264 + d * 33 + lp;
        C[(((size_t)(b << 8) + s2) << 9) + k1base + kk] = make_float2(sR[addr], sI[addr]);
    }
}

// fftB: k1-transform + apod + fused min/max; stores img transposed.
__global__ __launch_bounds__(256) void fftB(
    const float2* __restrict__ C, float* __restrict__ imgT, float beta2,
    unsigned* __restrict__ mmin, unsigned* __restrict__ mmax)
{
    __shared__ float2 tw[256];
    int t = threadIdx.x;
    int lane = t & 63;
    int w = t >> 6;
    int rowid = blockIdx.x * 4 + w;               // [0,2048) = b*256 + s2
    int b = rowid >> 8;
    int s2 = rowid & 255;

    {
        float ang = (float)(2.0 * M_PI / 512.0) * (float)t;
        float s, c; sincosf(ang, &s, &c);
        tw[t] = make_float2(c, s);
    }

    const float2* row = C + ((size_t)rowid << 9);
    int p = __brev((unsigned)lane) >> 26;
    float xr[8], xi[8];
#pragma unroll
    for (int a = 0; a < 8; ++a) {
        float2 v = row[p + (a << 6)];
        xr[a] = v.x; xi[a] = v.y;
    }
    __syncthreads();                       // table ready

    wave_fft512(xr, xi, lane, tw);

    const float XF = (float)(M_PI * (double)JJ / (double)KK);
    const float INVK2 = 1.0f / ((float)KK * (float)KK);
    float ns = (float)(s2 - 128);
    float xfs = XF * ns;
    float asq = beta2 - xfs * xfs;
    float ssq = sqrtf(asq);
    float ds = sinhf(ssq) / ssq;                  // wave-uniform
    float sbase = INVK2 / ds;

    bool act = (lane < 16) | (lane >= 48);
    int lpp = (lane < 16) ? lane : (lane - 32);
    float lmin = 1e30f, lmax = -1e30f;
    if (act) {
        float vals[8];
#pragma unroll
        for (int d = 0; d < 8; ++d) {
            int r = (8 * lpp + d + 128) & 255;
            float nr = (float)(r - 128);
            float xfr = XF * nr;
            float arq = beta2 - xfr * xfr;
            float srq = sqrtf(arq);
            float dr = sinhf(srq) / srq;
            float o = xr[d] * sbase / dr;
            vals[d] = o;
            lmin = fminf(lmin, o);
            lmax = fmaxf(lmax, o);
        }
        int r0run = (8 * lpp + 128) & 255;        // 8-run never straddles wrap
        float4* dst = (float4*)(imgT + ((size_t)b << 16) + (s2 << 8) + r0run);
        dst[0] = make_float4(vals[0], vals[1], vals[2], vals[3]);
        dst[1] = make_float4(vals[4], vals[5], vals[6], vals[7]);
    }
#pragma unroll
    for (int off = 32; off >= 1; off >>= 1) {
        lmin = fminf(lmin, __shfl_xor(lmin, off, 64));
        lmax = fmaxf(lmax, __shfl_xor(lmax, off, 64));
    }
    if (lane == 0) {
        atomicMin(&mmin[b], fkey(lmin));
        atomicMax(&mmax[b], fkey(lmax));
    }
}

// norm_t: normalize + transpose imgT[b][s2][r] -> out[b][r][s2].
__global__ __launch_bounds__(256) void norm_t(
    const float* __restrict__ imgT, const unsigned* __restrict__ mmin,
    const unsigned* __restrict__ mmax, float* __restrict__ out)
{
    __shared__ float tile[64][65];
    int b = blockIdx.x >> 4;
    int tl = blockIdx.x & 15;
    int r0 = (tl & 3) << 6;
    int s0 = (tl >> 2) << 6;
    int tr = threadIdx.x & 63;
    int ts = threadIdx.x >> 6;        // [0,4)

    const float* src = imgT + ((size_t)b << 16);
#pragma unroll
    for (int q = 0; q < 16; ++q) {
        int s2 = s0 + (q << 2) + ts;
        tile[s2 - s0][tr] = src[(s2 << 8) + r0 + tr];
    }
    __syncthreads();

    float mn = funkey(mmin[b]);
    float inv = 1.0f / (funkey(mmax[b]) - mn);
    float* dst = out + ((size_t)b << 16);
#pragma unroll
    for (int q = 0; q < 16; ++q) {
        int r = r0 + (q << 2) + ts;
        dst[(r << 8) + s0 + tr] = (tile[tr][r - r0] - mn) * inv;
    }
}

// ---------- host ----------

static double i0_host(double x) {
    double sum = 1.0, term = 1.0;
    double q = x * x * 0.25;
    for (int k = 1; k < 80; ++k) {
        term *= q / ((double)k * (double)k);
        sum += term;
        if (term < sum * 1e-17) break;
    }
    return sum;
}

extern "C" void kernel_launch(void* const* d_in, const int* in_sizes, int n_in,
                              void* d_out, int out_size, void* d_ws, size_t ws_size,
                              hipStream_t stream)
{
    const float* y_real  = (const float*)d_in[0];
    const float* y_imag  = (const float*)d_in[1];
    const float* weights = (const float*)d_in[2];
    const float2* uv2    = (const float2*)d_in[3];
    float* out = (float*)d_out;

    char* W = (char*)d_ws;
    // Aliased live ranges (peak ~24.4 MB):
    //  W[0,16M): counts[1M]+desc[2K] (binning) -> grid (gather->fftA) -> imgT [0,2M)
    //  A=W+16M:  rec [0,6.4M) + offsets [6.4M,7.45M) (bin->gather)
    //            -> C [0,8M) (fftA->fftB);  mm at [8.4M); lut at [8.4M+128)
    float*    grid    = (float*)W;                         // 16 MB
    int*      counts  = (int*)W;                           // 1 MB (aliases grid)
    unsigned long long* desc = (unsigned long long*)(W + 0x100000);  // 2 KB
    float*    imgT    = (float*)W;                         // 2 MB (aliases grid)
    char*     A       = W + (size_t)16 * 1024 * 1024;
    char*     rec     = A;                                 // 6,400,000 B
    int*      offsets = (int*)(A + 6400000);               // 1,048,580 B
    float2*   C       = (float2*)A;                        // 8 MB (aliases rec)
    unsigned* mmin    = (unsigned*)(A + 8400000);          // 32 B
    unsigned* mmax    = (unsigned*)(A + 8400064);          // 32 B
    float*    lut     = (float*)(A + 8400128);             // 4 KB

    double beta_d = M_PI * sqrt(19.45);   // BETA with alpha=2
    float beta = (float)beta_d;
    float inv_i0b = (float)(1.0 / i0_host(beta_d));
    float beta2 = (float)(beta_d * beta_d);

    // one memset covers counts (1 MB) + desc (2 KB)
    hipMemsetAsync(counts, 0, NBINS * sizeof(int) + 256 * sizeof(unsigned long long),
                   stream);

    count_bins<<<(MPTS + 255) / 256, 256, 0, stream>>>(
        uv2, counts, mmin, mmax, lut, beta, inv_i0b);

    scan_k<<<256, 1024, 0, stream>>>(counts, offsets, desc);

    fill_records<<<(MPTS + 255) / 256, 256, 0, stream>>>(
        uv2, y_real, y_imag, weights, offsets, counts, rec, lut);

    gather_grid<<<2048, 256, 0, stream>>>(offsets, rec, grid);

    fftA<<<512, 512, 0, stream>>>((const float2*)grid, C);

    fftB<<<512, 256, 0, stream>>>(C, imgT, beta2, mmin, mmax);

    norm_t<<<128, 256, 0, stream>>>(imgT, mmin, mmax, out);
}

// Round 13
// 148.343 us; speedup vs baseline: 1.1424x; 1.1424x over previous
//
#include <hip/hip_runtime.h>
#include <math.h>

// Problem constants
#define NN 256
#define KK 512
#define JJ 6
#define BB 8
#define MPTS 100000
#define NBINS (KK * KK)
// K/(2*pi)
#define KF_SCALE 81.48733086305615f

typedef _Float16 h8 __attribute__((ext_vector_type(8)));

// ---------- device helpers ----------

// Abramowitz & Stegun 9.8.1 / 9.8.2 modified Bessel I0, float
__device__ __forceinline__ float i0f_dev(float x) {
    float ax = fabsf(x);
    if (ax < 3.75f) {
        float t = x / 3.75f; t *= t;
        return 1.0f + t*(3.5156229f + t*(3.0899424f + t*(1.2067492f +
               t*(0.2659732f + t*(0.0360768f + t*0.0045813f)))));
    } else {
        float t = 3.75f / ax;
        return (expf(ax) * rsqrtf(ax)) *
               (0.39894228f + t*(0.01328592f + t*(0.00225319f + t*(-0.00157565f +
                t*(0.00916281f + t*(-0.02057706f + t*(0.02635537f +
                t*(-0.01647633f + t*0.00392377f))))))));
    }
}

__device__ __forceinline__ float kbf(float t, float beta, float inv_i0b) {
    float u = t * (1.0f / 3.0f);       // 2*t/J, J=6
    float q = fmaxf(1.0f - u * u, 0.0f);
    return i0f_dev(beta * sqrtf(q)) * inv_i0b;
}

// inclusive wave scan (64 lanes)
__device__ __forceinline__ int wave_scan(int x, int lane) {
#pragma unroll
    for (int off = 1; off < 64; off <<= 1) {
        int y = __shfl_up(x, off, 64);
        if (lane >= off) x += y;
    }
    return x;
}

// KB weight via 1024-entry LUT over t in [-3,3], linear interp (err ~4e-4)
__device__ __forceinline__ float kb_lut(const float* __restrict__ sT, float t) {
    float u = (t + 3.0f) * (1023.0f / 6.0f);   // t in (-3, 3] -> u in (0, 1023]
    int i = (int)u;
    i = min(i, 1022);
    float f = u - (float)i;
    float a = sT[i];
    return a + f * (sT[i + 1] - sT[i]);
}

// ---------- binning kernels ----------

// count_bins also builds the KB LUT (threads 0..1023 of block 0 span).
__global__ __launch_bounds__(256) void count_bins(
    const float2* __restrict__ uv2, int* __restrict__ counts,
    float* __restrict__ lut, float beta, float inv_i0b)
{
    int m = blockIdx.x * 256 + threadIdx.x;
    if (m < 1024) {
        float t = -3.0f + (6.0f / 1023.0f) * (float)m;
        lut[m] = kbf(t, beta, inv_i0b);
    }
    if (m >= MPTS) return;
    float2 u = uv2[m];
    int b0 = (int)floorf(u.x * KF_SCALE) & (KK - 1);
    int b1 = (int)floorf(u.y * KF_SCALE) & (KK - 1);
    atomicAdd(&counts[(b0 << 9) | b1], 1);
}

// Single-pass decoupled-lookback exclusive scan of counts[262144] -> offsets.
__global__ __launch_bounds__(1024) void scan_k(
    const int* __restrict__ counts, int* __restrict__ offsets,
    unsigned long long* __restrict__ desc)
{
    __shared__ int part[16];
    __shared__ int s_prefix;
    int tid = threadIdx.x;
    int lane = tid & 63;
    int w = tid >> 6;                       // [0,16)
    int g = blockIdx.x * 1024 + tid;

    int v = counts[g];
    int x = wave_scan(v, lane);
    if (lane == 63) part[w] = x;
    __syncthreads();
    if (tid < 16) {
        int p = part[tid];
#pragma unroll
        for (int off = 1; off < 16; off <<= 1) {
            int y = __shfl_up(p, off, 64);
            if (tid >= off) p += y;
        }
        part[tid] = p;
    }
    __syncthreads();
    int incl = x + ((w > 0) ? part[w - 1] : 0);
    int total = part[15];                   // block aggregate

    if (tid == 0) {
        unsigned long long pack = ((unsigned long long)(unsigned)total << 2) |
                                  ((blockIdx.x == 0) ? 2ULL : 1ULL);
        atomicExch(&desc[blockIdx.x], pack);
        if (blockIdx.x == 0) s_prefix = 0;
    }

    if (blockIdx.x > 0 && w == 0) {
        int prefix = 0;
        int base = blockIdx.x - 1;
        bool done = false;
        while (!done) {
            int idx = base - lane;          // lane 0 = nearest predecessor
            unsigned long long d = 0;
            if (idx >= 0) {
                do { d = atomicAdd(&desc[idx], 0ULL); } while ((d & 3ULL) == 0ULL);
            }
            unsigned long long mask = __ballot(idx >= 0 && (d & 3ULL) == 2ULL);
            int f = (mask != 0ULL) ? (__ffsll((long long)mask) - 1) : 64;
            int contrib = (idx >= 0 && lane <= f) ? (int)(d >> 2) : 0;
#pragma unroll
            for (int off = 1; off < 64; off <<= 1)
                contrib += __shfl_xor(contrib, off, 64);
            prefix += contrib;
            base -= 64;
            done = (mask != 0ULL);
        }
        if (lane == 0) {
            s_prefix = prefix;
            atomicExch(&desc[blockIdx.x],
                       ((unsigned long long)(unsigned)(prefix + total) << 2) | 2ULL);
        }
    }
    __syncthreads();

    offsets[g] = incl - v + s_prefix;
    if (g == 0) offsets[NBINS] = MPTS;
}

// fill_records: 64B record per point, written to its CSR slot (sorted by bin):
//  [0,12)  w0[6]  f16 axis-0 KB weights
//  [12,24) w1[6]  f16 axis-1 KB weights
//  [24,28) bin1   int (c1 coordinate of the point's bin)
//  [28,32) pad
//  [32,64) y      16 x f16: 8 batches, (re,im) pairs, pre-weighted
__global__ __launch_bounds__(256) void fill_records(
    const float2* __restrict__ uv2,
    const float* __restrict__ y_real, const float* __restrict__ y_imag,
    const float* __restrict__ weights, const int* __restrict__ offsets,
    int* __restrict__ counts, char* __restrict__ rec,
    const float* __restrict__ lut)
{
    __shared__ float sT[1024];
    int tid = threadIdx.x;
#pragma unroll
    for (int q = 0; q < 4; ++q) sT[q * 256 + tid] = lut[q * 256 + tid];
    __syncthreads();

    int m = blockIdx.x * 256 + tid;
    if (m >= MPTS) return;
    float2 u = uv2[m];
    float kf0 = u.x * KF_SCALE;
    float kf1 = u.y * KF_SCALE;
    float f0 = floorf(kf0), f1 = floorf(kf1);
    float fr0 = kf0 - f0, fr1 = kf1 - f1;
    int b1c = (int)f1 & (KK - 1);
    int bin = (((int)f0 & (KK - 1)) << 9) | b1c;
    int old = atomicSub(&counts[bin], 1);
    int slot = offsets[bin] + old - 1;

    _Float16 hw[12];
#pragma unroll
    for (int j = 0; j < JJ; ++j) {
        hw[j]     = (_Float16)kb_lut(sT, (float)(j - 2) - fr0);
        hw[6 + j] = (_Float16)kb_lut(sT, (float)(j - 2) - fr1);
    }

    float4 c0v, c1v;
    _Float16* p0 = (_Float16*)&c0v;
    _Float16* p1 = (_Float16*)&c1v;
#pragma unroll
    for (int j = 0; j < 8; ++j) p0[j] = hw[j];        // w0[0..5], w1[0..1]
#pragma unroll
    for (int j = 0; j < 4; ++j) p1[j] = hw[8 + j];    // w1[2..5]
    ((int*)&c1v)[2] = b1c;
    ((int*)&c1v)[3] = 0;

    float wm = weights[m];
    h8 ha, hb;
#pragma unroll
    for (int b = 0; b < 4; ++b) {
        ha[2 * b]     = (_Float16)(y_real[b * MPTS + m] * wm);
        ha[2 * b + 1] = (_Float16)(y_imag[b * MPTS + m] * wm);
        hb[2 * b]     = (_Float16)(y_real[(b + 4) * MPTS + m] * wm);
        hb[2 * b + 1] = (_Float16)(y_imag[(b + 4) * MPTS + m] * wm);
    }

    float4* dst = (float4*)(rec + (size_t)slot * 64);
    dst[0] = c0v;
    dst[1] = c1v;
    dst[2] = *(float4*)&ha;
    dst[3] = *(float4*)&hb;
}

// ---------- gather v6: 32 cells/wave, 2 lanes/cell, 8 waves/SIMD ----------
__global__ __launch_bounds__(256) void gather_grid(
    const int* __restrict__ offsets, const char* __restrict__ rec,
    float* __restrict__ grid)
{
    __shared__ __align__(16) char lds[4][2816];   // 32 pts x 88B per wave
    int t = threadIdx.x;
    int lane = t & 63;
    int w = t >> 6;
    int half = lane >> 5;              // 0: batches 0-3, 1: batches 4-7
    int l32 = lane & 31;
    int j = blockIdx.x;                // 2048 blocks: xcd(3) | c0low(6) | q(2)
    int xcd = j & 7;
    int c0 = (xcd << 6) + ((j >> 3) & 63);
    int q4 = j >> 9;                   // [0,4)
    int c1base = (q4 << 7) + (w << 5); // [0,512) step 32
    int c1 = c1base + l32;
    int wa = c1 - 3, wb = c1 + 2;      // lane's bin window (unwrapped)

    char* myl = lds[w];

    float aR[4], aI[4];
#pragma unroll
    for (int b = 0; b < 4; ++b) { aR[b] = 0.0f; aI[b] = 0.0f; }

    for (int j0 = 0; j0 < JJ; ++j0) {
        int r0 = (c0 - (j0 - 2)) & (KK - 1);
        int rowbase = r0 << 9;
        int lo = c1base - 3, hi = c1base + 33;
        int nseg, ga0, gb0, ga1, gb1;
        if (lo < 0)        { ga0 = lo; gb0 = -1;  ga1 = 0;   gb1 = hi; nseg = 2; }
        else if (hi > 511) { ga0 = lo; gb0 = 511; ga1 = 512; gb1 = hi; nseg = 2; }
        else               { ga0 = lo; gb0 = hi;  ga1 = 0;   gb1 = 0;  nseg = 1; }

        for (int sgi = 0; sgi < nseg; ++sgi) {
            int ga = sgi ? ga1 : ga0;
            int gb = sgi ? gb1 : gb0;
            int pstart = offsets[rowbase + (ga & 511)];          // wave-uniform
            int pend   = offsets[rowbase + ((gb & 511) + 1)];    // wave-uniform
            int ia = max(wa, ga), ib = min(wb, gb);
            bool has = ia <= ib;
            int pA = has ? offsets[rowbase + (ia & 511)] : 0;
            int pB = has ? ((ib == gb) ? pend
                                       : offsets[rowbase + ((ib + 1) & 511)]) : 0;

            for (int pc = pstart; pc < pend; pc += 32) {
                int cnt = min(32, pend - pc);
                int sub = lane & 3;
                int prow = lane >> 2;      // [0,16)
#pragma unroll
                for (int qq = 0; qq < 2; ++qq) {
                    if (16 * qq < cnt) {
                        int pp = min(pc + prow + 16 * qq, MPTS - 1);
                        float4 v = *(const float4*)(rec + (size_t)pp * 64 + sub * 16);
                        *(float4*)(myl + (prow + 16 * qq) * 88 + sub * 16) = v;
                    }
                }
                int pLo = max(pA, pc), pHi = min(pB, pc + cnt);
                for (int p = pLo; p < pHi; ++p) {
                    const char* rp = myl + (p - pc) * 88;
                    int bin1 = *(const int*)(rp + 24);
                    int idx = (c1 - bin1 + 2) & 511;   // wrap-exact o1+2
                    bool ok = idx <= 5;
                    idx = ok ? idx : 0;
                    float w0 = (float)*(const _Float16*)(rp + j0 * 2);
                    float w1 = (float)*(const _Float16*)(rp + 12 + idx * 2);
                    float ww = ok ? w0 * w1 : 0.0f;
                    h8 yv = *(const h8*)(rp + 32 + (half << 4));
#pragma unroll
                    for (int b = 0; b < 4; ++b) {
                        aR[b] += (float)yv[2 * b]     * ww;   // v_fma_mix
                        aI[b] += (float)yv[2 * b + 1] * ww;
                    }
                }
            }
        }
    }

    float2* g2 = (float2*)grid;
    int c = (c0 << 9) + c1;
#pragma unroll
    for (int b = 0; b < 4; ++b)
        g2[((size_t)((half << 2) + b) << 18) + c] = make_float2(aR[b], aI[b]);
}

// ---------- per-wave 512-pt FFT: 8(reg) x 64(lanes via shfl), sign +i ----------
// Initial twiddle from LDS table (conflict-light permuted read); stage
// twiddles via sincosf (conflict-free, proven r10).
__device__ __forceinline__ void wave_fft512(float xr[8], float xi[8], int lane,
                                            const float2* __restrict__ tw)
{
    float a0r = xr[0]+xr[4], a0i = xi[0]+xi[4];
    float a4r = xr[0]-xr[4], a4i = xi[0]-xi[4];
    float a2r = xr[2]+xr[6], a2i = xi[2]+xi[6];
    float a6r = xr[2]-xr[6], a6i = xi[2]-xi[6];
    float a1r = xr[1]+xr[5], a1i = xi[1]+xi[5];
    float a5r = xr[1]-xr[5], a5i = xi[1]-xi[5];
    float a3r = xr[3]+xr[7], a3i = xi[3]+xi[7];
    float a7r = xr[3]-xr[7], a7i = xi[3]-xi[7];
    float b0r = a0r+a2r, b0i = a0i+a2i;
    float b2r = a0r-a2r, b2i = a0i-a2i;
    float b4r = a4r-a6i, b4i = a4i+a6r;    // a4 + i*a6
    float b6r = a4r+a6i, b6i = a4i-a6r;    // a4 - i*a6
    float b1r = a1r+a3r, b1i = a1i+a3i;
    float b3r = a1r-a3r, b3i = a1i-a3i;
    float b5r = a5r-a7i, b5i = a5i+a7r;
    float b7r = a5r+a7i, b7i = a5i-a7r;
    const float S2 = 0.70710678118654752f;
    float w5r = S2*(b5r-b5i), w5i = S2*(b5r+b5i);     // W8^1 * b5
    float w7r = -S2*(b7r+b7i), w7i = S2*(b7r-b7i);    // W8^3 * b7
    float y0r = b0r+b1r, y0i = b0i+b1i;
    float y4r = b0r-b1r, y4i = b0i-b1i;
    float y1r = b4r+w5r, y1i = b4i+w5i;
    float y5r = b4r-w5r, y5i = b4i-w5i;
    float y2r = b2r-b3i, y2i = b2i+b3r;    // b2 + i*b3
    float y6r = b2r+b3i, y6i = b2i-b3r;
    float y3r = b6r+w7r, y3i = b6i+w7i;
    float y7r = b6r-w7r, y7i = b6i-w7i;

    // T[d] = Y[d] * w^(p*d), w = e^{+2pi i p/512} from table, p = brev6(lane)
    int p = __brev((unsigned)lane) >> 26;
    float2 w0v = tw[p];
    float c1 = w0v.x, s1 = w0v.y;
    float wr = c1, wi = s1, tr;
    xr[0] = y0r; xi[0] = y0i;
    xr[1] = y1r*wr - y1i*wi; xi[1] = y1i*wr + y1r*wi;
    tr = wr*c1 - wi*s1; wi = wr*s1 + wi*c1; wr = tr;
    xr[2] = y2r*wr - y2i*wi; xi[2] = y2i*wr + y2r*wi;
    tr = wr*c1 - wi*s1; wi = wr*s1 + wi*c1; wr = tr;
    xr[3] = y3r*wr - y3i*wi; xi[3] = y3i*wr + y3r*wi;
    tr = wr*c1 - wi*s1; wi = wr*s1 + wi*c1; wr = tr;
    xr[4] = y4r*wr - y4i*wi; xi[4] = y4i*wr + y4r*wi;
    tr = wr*c1 - wi*s1; wi = wr*s1 + wi*c1; wr = tr;
    xr[5] = y5r*wr - y5i*wi; xi[5] = y5i*wr + y5r*wi;
    tr = wr*c1 - wi*s1; wi = wr*s1 + wi*c1; wr = tr;
    xr[6] = y6r*wr - y6i*wi; xi[6] = y6i*wr + y6r*wi;
    tr = wr*c1 - wi*s1; wi = wr*s1 + wi*c1; wr = tr;
    xr[7] = y7r*wr - y7i*wi; xi[7] = y7i*wr + y7r*wi;

    // cross-lane FFT64 over p (stage twiddles via sincosf, conflict-free)
#pragma unroll
    for (int t = 0; t < 6; ++t) {
        int m = 1 << t;
        int j = lane & (m - 1);
        float wc, wsn;
        sincosf((float)M_PI * (float)j / (float)m, &wsn, &wc);  // e^{+2pi i j/(2m)}
        bool hi = (lane & m) != 0;
#pragma unroll
        for (int d = 0; d < 8; ++d) {
            float pR = __shfl_xor(xr[d], m, 64);
            float pI = __shfl_xor(xi[d], m, 64);
            float bR = hi ? xr[d] : pR;
            float bI = hi ? xi[d] : pI;
            float aR = hi ? pR : xr[d];
            float aI = hi ? pI : xi[d];
            float wbR = wc * bR - wsn * bI;
            float wbI = wc * bI + wsn * bR;
            xr[d] = hi ? aR - wbR : aR + wbR;
            xi[d] = hi ? aI - wbI : aI + wbI;
        }
    }
}

// fftA: k2-transform. 512 blocks x 8 waves; wave = row (b, k1).
__global__ __launch_bounds__(512) void fftA(
    const float2* __restrict__ grid2, float2* __restrict__ C)
{
    __shared__ float sR[2112], sI[2112];   // 8 waves * 264, stride33 swizzle
    __shared__ float2 tw[256];
    int t = threadIdx.x;
    int lane = t & 63;
    int w = t >> 6;
    int b = blockIdx.x & 7;
    int k1base = (blockIdx.x >> 3) << 3;
    int k1 = k1base + w;

    if (t < 256) {
        float ang = (float)(2.0 * M_PI / 512.0) * (float)t;
        float s, c; sincosf(ang, &s, &c);
        tw[t] = make_float2(c, s);
    }

    const float2* row = grid2 + ((size_t)b << 18) + ((size_t)k1 << 9);
    int p = __brev((unsigned)lane) >> 26;
    float xr[8], xi[8];
#pragma unroll
    for (int a = 0; a < 8; ++a) {
        float2 v = row[p + (a << 6)];
        xr[a] = v.x; xi[a] = v.y;
    }
    __syncthreads();                       // table ready

    wave_fft512(xr, xi, lane, tw);

    bool act = (lane < 16) | (lane >= 48);
    int lpp = (lane < 16) ? lane : (lane - 32);   // [0,32)
    if (act) {
#pragma unroll
        for (int d = 0; d < 8; ++d) {
            int addr = w * 264 + d * 33 + lpp;    // conflict-free swizzle
            sR[addr] = xr[d];
            sI[addr] = xi[d];
        }
    }
    __syncthreads();

#pragma unroll
    for (int pp = 0; pp < 4; ++pp) {
        int idx = pp * 512 + t;                   // [0,2048) = 256 s2 x 8 k1
        int kk = idx & 7;
        int s2 = idx >> 3;
        int v = (s2 + 128) & 255;                 // v = 8*lpp + d
        int d = v & 7;
        int lp = v >> 3;
        int addr = kk * 264 + d * 33 + lp;
        C[(((size_t)(b << 8) + s2) << 9) + k1base + kk] = make_float2(sR[addr], sI[addr]);
    }
}

// fftB: k1-transform + apod (LDS table) + block-reduced min/max (no atomics);
// stores img transposed. pmin/pmax[blk] written with plain stores.
__global__ __launch_bounds__(256) void fftB(
    const float2* __restrict__ C, float* __restrict__ imgT, float beta2,
    float* __restrict__ pmin, float* __restrict__ pmax)
{
    __shared__ float2 tw[256];
    __shared__ float invd[256];
    __shared__ float wmn[4], wmx[4];
    int t = threadIdx.x;
    int lane = t & 63;
    int w = t >> 6;
    int rowid = blockIdx.x * 4 + w;               // [0,2048) = b*256 + s2
    int b = rowid >> 8;                           // same for all 4 waves (4|256)
    int s2 = rowid & 255;

    {
        float ang = (float)(2.0 * M_PI / 512.0) * (float)t;
        float s, c; sincosf(ang, &s, &c);
        tw[t] = make_float2(c, s);
        // apodization reciprocal table: invd[i] = 1/d(i-128)
        const float XF = (float)(M_PI * (double)JJ / (double)KK);
        float n = (float)(t - 128);
        float xf = XF * n;
        float arg = beta2 - xf * xf;
        float sq = sqrtf(arg);
        invd[t] = sq / sinhf(sq);
    }

    const float2* row = C + ((size_t)rowid << 9);
    int p = __brev((unsigned)lane) >> 26;
    float xr[8], xi[8];
#pragma unroll
    for (int a = 0; a < 8; ++a) {
        float2 v = row[p + (a << 6)];
        xr[a] = v.x; xi[a] = v.y;
    }
    __syncthreads();                       // tables ready

    wave_fft512(xr, xi, lane, tw);

    const float INVK2 = 1.0f / ((float)KK * (float)KK);
    float sbase = INVK2 * invd[s2];               // wave-uniform broadcast

    bool act = (lane < 16) | (lane >= 48);
    int lpp = (lane < 16) ? lane : (lane - 32);
    float lmin = 1e30f, lmax = -1e30f;
    if (act) {
        float vals[8];
#pragma unroll
        for (int d = 0; d < 8; ++d) {
            int r = (8 * lpp + d + 128) & 255;
            float o = xr[d] * sbase * invd[r];
            vals[d] = o;
            lmin = fminf(lmin, o);
            lmax = fmaxf(lmax, o);
        }
        int r0run = (8 * lpp + 128) & 255;        // 8-run never straddles wrap
        float4* dst = (float4*)(imgT + ((size_t)b << 16) + (s2 << 8) + r0run);
        dst[0] = make_float4(vals[0], vals[1], vals[2], vals[3]);
        dst[1] = make_float4(vals[4], vals[5], vals[6], vals[7]);
    }
#pragma unroll
    for (int off = 32; off >= 1; off >>= 1) {
        lmin = fminf(lmin, __shfl_xor(lmin, off, 64));
        lmax = fmaxf(lmax, __shfl_xor(lmax, off, 64));
    }
    if (lane == 0) { wmn[w] = lmin; wmx[w] = lmax; }
    __syncthreads();
    if (t == 0) {
        float mn = fminf(fminf(wmn[0], wmn[1]), fminf(wmn[2], wmn[3]));
        float mx = fmaxf(fmaxf(wmx[0], wmx[1]), fmaxf(wmx[2], wmx[3]));
        pmin[blockIdx.x] = mn;                    // plain stores, no contention
        pmax[blockIdx.x] = mx;
    }
}

// norm_t: normalize + transpose imgT[b][s2][r] -> out[b][r][s2].
// Reduces the batch's 64 block-partials at block start (wave 0).
__global__ __launch_bounds__(256) void norm_t(
    const float* __restrict__ imgT, const float* __restrict__ pmin,
    const float* __restrict__ pmax, float* __restrict__ out)
{
    __shared__ float tile[64][65];
    __shared__ float s_mn, s_inv;
    int b = blockIdx.x >> 4;
    int tl = blockIdx.x & 15;
    int r0 = (tl & 3) << 6;
    int s0 = (tl >> 2) << 6;
    int tr = threadIdx.x & 63;
    int ts = threadIdx.x >> 6;        // [0,4)

    if (threadIdx.x < 64) {           // fftB blocks [64b, 64b+64) = batch b
        float mn = pmin[(b << 6) + threadIdx.x];
        float mx = pmax[(b << 6) + threadIdx.x];
#pragma unroll
        for (int off = 32; off >= 1; off >>= 1) {
            mn = fminf(mn, __shfl_xor(mn, off, 64));
            mx = fmaxf(mx, __shfl_xor(mx, off, 64));
        }
        if (threadIdx.x == 0) { s_mn = mn; s_inv = 1.0f / (mx - mn); }
    }

    const float* src = imgT + ((size_t)b << 16);
#pragma unroll
    for (int q = 0; q < 16; ++q) {
        int s2 = s0 + (q << 2) + ts;
        tile[s2 - s0][tr] = src[(s2 << 8) + r0 + tr];
    }
    __syncthreads();

    float mn = s_mn, inv = s_inv;
    float* dst = out + ((size_t)b << 16);
#pragma unroll
    for (int q = 0; q < 16; ++q) {
        int r = r0 + (q << 2) + ts;
        dst[(r << 8) + s0 + tr] = (tile[tr][r - r0] - mn) * inv;
    }
}

// ---------- host ----------

static double i0_host(double x) {
    double sum = 1.0, term = 1.0;
    double q = x * x * 0.25;
    for (int k = 1; k < 80; ++k) {
        term *= q / ((double)k * (double)k);
        sum += term;
        if (term < sum * 1e-17) break;
    }
    return sum;
}

extern "C" void kernel_launch(void* const* d_in, const int* in_sizes, int n_in,
                              void* d_out, int out_size, void* d_ws, size_t ws_size,
                              hipStream_t stream)
{
    const float* y_real  = (const float*)d_in[0];
    const float* y_imag  = (const float*)d_in[1];
    const float* weights = (const float*)d_in[2];
    const float2* uv2    = (const float2*)d_in[3];
    float* out = (float*)d_out;

    char* W = (char*)d_ws;
    // Aliased live ranges (peak ~24.4 MB):
    //  W[0,16M): counts[1M]+desc[2K] (binning) -> grid (gather->fftA) -> imgT [0,2M)
    //  A=W+16M:  rec [0,6.4M) + offsets [6.4M,7.45M) (bin->gather)
    //            -> C [0,8M) (fftA->fftB); pmin/pmax at [8.4M); lut at [8.41M)
    float*    grid    = (float*)W;                         // 16 MB
    int*      counts  = (int*)W;                           // 1 MB (aliases grid)
    unsigned long long* desc = (unsigned long long*)(W + 0x100000);  // 2 KB
    float*    imgT    = (float*)W;                         // 2 MB (aliases grid)
    char*     A       = W + (size_t)16 * 1024 * 1024;
    char*     rec     = A;                                 // 6,400,000 B
    int*      offsets = (int*)(A + 6400000);               // 1,048,580 B
    float2*   C       = (float2*)A;                        // 8 MB (aliases rec)
    float*    pmin    = (float*)(A + 8400000);             // 2 KB
    float*    pmax    = (float*)(A + 8402048);             // 2 KB
    float*    lut     = (float*)(A + 8404096);             // 4 KB

    double beta_d = M_PI * sqrt(19.45);   // BETA with alpha=2
    float beta = (float)beta_d;
    float inv_i0b = (float)(1.0 / i0_host(beta_d));
    float beta2 = (float)(beta_d * beta_d);

    // one memset covers counts (1 MB) + desc (2 KB)
    hipMemsetAsync(counts, 0, NBINS * sizeof(int) + 256 * sizeof(unsigned long long),
                   stream);

    count_bins<<<(MPTS + 255) / 256, 256, 0, stream>>>(
        uv2, counts, lut, beta, inv_i0b);

    scan_k<<<256, 1024, 0, stream>>>(counts, offsets, desc);

    fill_records<<<(MPTS + 255) / 256, 256, 0, stream>>>(
        uv2, y_real, y_imag, weights, offsets, counts, rec, lut);

    gather_grid<<<2048, 256, 0, stream>>>(offsets, rec, grid);

    fftA<<<512, 512, 0, stream>>>((const float2*)grid, C);

    fftB<<<512, 256, 0, stream>>>(C, imgT, beta2, pmin, pmax);

    norm_t<<<128, 256, 0, stream>>>(imgT, pmin, pmax, out);
}

// Round 14
// 142.054 us; speedup vs baseline: 1.1930x; 1.0443x over previous
//
#include <hip/hip_runtime.h>
#include <math.h>

// Problem constants
#define NN 256
#define KK 512
#define JJ 6
#define BB 8
#define MPTS 100000
#define NBINS (KK * KK)
// K/(2*pi)
#define KF_SCALE 81.48733086305615f

typedef _Float16 h8 __attribute__((ext_vector_type(8)));

// ---------- device helpers ----------

// Abramowitz & Stegun 9.8.1 / 9.8.2 modified Bessel I0, float
__device__ __forceinline__ float i0f_dev(float x) {
    float ax = fabsf(x);
    if (ax < 3.75f) {
        float t = x / 3.75f; t *= t;
        return 1.0f + t*(3.5156229f + t*(3.0899424f + t*(1.2067492f +
               t*(0.2659732f + t*(0.0360768f + t*0.0045813f)))));
    } else {
        float t = 3.75f / ax;
        return (expf(ax) * rsqrtf(ax)) *
               (0.39894228f + t*(0.01328592f + t*(0.00225319f + t*(-0.00157565f +
                t*(0.00916281f + t*(-0.02057706f + t*(0.02635537f +
                t*(-0.01647633f + t*0.00392377f))))))));
    }
}

__device__ __forceinline__ float kbf(float t, float beta, float inv_i0b) {
    float u = t * (1.0f / 3.0f);       // 2*t/J, J=6
    float q = fmaxf(1.0f - u * u, 0.0f);
    return i0f_dev(beta * sqrtf(q)) * inv_i0b;
}

// inclusive wave scan (64 lanes)
__device__ __forceinline__ int wave_scan(int x, int lane) {
#pragma unroll
    for (int off = 1; off < 64; off <<= 1) {
        int y = __shfl_up(x, off, 64);
        if (lane >= off) x += y;
    }
    return x;
}

// KB weight via 1024-entry LUT over t in [-3,3], linear interp (err ~4e-4)
__device__ __forceinline__ float kb_lut(const float* __restrict__ sT, float t) {
    float u = (t + 3.0f) * (1023.0f / 6.0f);
    int i = (int)u;
    i = min(i, 1022);
    float f = u - (float)i;
    float a = sT[i];
    return a + f * (sT[i + 1] - sT[i]);
}

// ---------- binning kernels ----------

// count_bins also builds the KB LUT.
__global__ __launch_bounds__(256) void count_bins(
    const float2* __restrict__ uv2, int* __restrict__ counts,
    float* __restrict__ lut, float beta, float inv_i0b)
{
    int m = blockIdx.x * 256 + threadIdx.x;
    if (m < 1024) {
        float t = -3.0f + (6.0f / 1023.0f) * (float)m;
        lut[m] = kbf(t, beta, inv_i0b);
    }
    if (m >= MPTS) return;
    float2 u = uv2[m];
    int b0 = (int)floorf(u.x * KF_SCALE) & (KK - 1);
    int b1 = (int)floorf(u.y * KF_SCALE) & (KK - 1);
    atomicAdd(&counts[(b0 << 9) | b1], 1);
}

// Single-pass decoupled-lookback exclusive scan of counts[262144] -> offsets.
__global__ __launch_bounds__(1024) void scan_k(
    const int* __restrict__ counts, int* __restrict__ offsets,
    unsigned long long* __restrict__ desc)
{
    __shared__ int part[16];
    __shared__ int s_prefix;
    int tid = threadIdx.x;
    int lane = tid & 63;
    int w = tid >> 6;                       // [0,16)
    int g = blockIdx.x * 1024 + tid;

    int v = counts[g];
    int x = wave_scan(v, lane);
    if (lane == 63) part[w] = x;
    __syncthreads();
    if (tid < 16) {
        int p = part[tid];
#pragma unroll
        for (int off = 1; off < 16; off <<= 1) {
            int y = __shfl_up(p, off, 64);
            if (tid >= off) p += y;
        }
        part[tid] = p;
    }
    __syncthreads();
    int incl = x + ((w > 0) ? part[w - 1] : 0);
    int total = part[15];                   // block aggregate

    if (tid == 0) {
        unsigned long long pack = ((unsigned long long)(unsigned)total << 2) |
                                  ((blockIdx.x == 0) ? 2ULL : 1ULL);
        atomicExch(&desc[blockIdx.x], pack);
        if (blockIdx.x == 0) s_prefix = 0;
    }

    if (blockIdx.x > 0 && w == 0) {
        int prefix = 0;
        int base = blockIdx.x - 1;
        bool done = false;
        while (!done) {
            int idx = base - lane;          // lane 0 = nearest predecessor
            unsigned long long d = 0;
            if (idx >= 0) {
                do { d = atomicAdd(&desc[idx], 0ULL); } while ((d & 3ULL) == 0ULL);
            }
            unsigned long long mask = __ballot(idx >= 0 && (d & 3ULL) == 2ULL);
            int f = (mask != 0ULL) ? (__ffsll((long long)mask) - 1) : 64;
            int contrib = (idx >= 0 && lane <= f) ? (int)(d >> 2) : 0;
#pragma unroll
            for (int off = 1; off < 64; off <<= 1)
                contrib += __shfl_xor(contrib, off, 64);
            prefix += contrib;
            base -= 64;
            done = (mask != 0ULL);
        }
        if (lane == 0) {
            s_prefix = prefix;
            atomicExch(&desc[blockIdx.x],
                       ((unsigned long long)(unsigned)(prefix + total) << 2) | 2ULL);
        }
    }
    __syncthreads();

    offsets[g] = incl - v + s_prefix;
    if (g == 0) offsets[NBINS] = MPTS;
}

// fill_records: 64B record per point, written to its CSR slot (sorted by bin).
__global__ __launch_bounds__(256) void fill_records(
    const float2* __restrict__ uv2,
    const float* __restrict__ y_real, const float* __restrict__ y_imag,
    const float* __restrict__ weights, const int* __restrict__ offsets,
    int* __restrict__ counts, char* __restrict__ rec,
    const float* __restrict__ lut)
{
    __shared__ float sT[1024];
    int tid = threadIdx.x;
#pragma unroll
    for (int q = 0; q < 4; ++q) sT[q * 256 + tid] = lut[q * 256 + tid];
    __syncthreads();

    int m = blockIdx.x * 256 + tid;
    if (m >= MPTS) return;
    float2 u = uv2[m];
    float kf0 = u.x * KF_SCALE;
    float kf1 = u.y * KF_SCALE;
    float f0 = floorf(kf0), f1 = floorf(kf1);
    float fr0 = kf0 - f0, fr1 = kf1 - f1;
    int b1c = (int)f1 & (KK - 1);
    int bin = (((int)f0 & (KK - 1)) << 9) | b1c;
    int old = atomicSub(&counts[bin], 1);
    int slot = offsets[bin] + old - 1;

    _Float16 hw[12];
#pragma unroll
    for (int j = 0; j < JJ; ++j) {
        hw[j]     = (_Float16)kb_lut(sT, (float)(j - 2) - fr0);
        hw[6 + j] = (_Float16)kb_lut(sT, (float)(j - 2) - fr1);
    }

    float4 c0v, c1v;
    _Float16* p0 = (_Float16*)&c0v;
    _Float16* p1 = (_Float16*)&c1v;
#pragma unroll
    for (int j = 0; j < 8; ++j) p0[j] = hw[j];        // w0[0..5], w1[0..1]
#pragma unroll
    for (int j = 0; j < 4; ++j) p1[j] = hw[8 + j];    // w1[2..5]
    ((int*)&c1v)[2] = b1c;
    ((int*)&c1v)[3] = 0;

    float wm = weights[m];
    h8 ha, hb;
#pragma unroll
    for (int b = 0; b < 4; ++b) {
        ha[2 * b]     = (_Float16)(y_real[b * MPTS + m] * wm);
        ha[2 * b + 1] = (_Float16)(y_imag[b * MPTS + m] * wm);
        hb[2 * b]     = (_Float16)(y_real[(b + 4) * MPTS + m] * wm);
        hb[2 * b + 1] = (_Float16)(y_imag[(b + 4) * MPTS + m] * wm);
    }

    float4* dst = (float4*)(rec + (size_t)slot * 64);
    dst[0] = c0v;
    dst[1] = c1v;
    dst[2] = *(float4*)&ha;
    dst[3] = *(float4*)&hb;
}

// ---------- gather v6: 32 cells/wave, 2 lanes/cell, 8 waves/SIMD ----------
__global__ __launch_bounds__(256) void gather_grid(
    const int* __restrict__ offsets, const char* __restrict__ rec,
    float* __restrict__ grid)
{
    __shared__ __align__(16) char lds[4][2816];   // 32 pts x 88B per wave
    int t = threadIdx.x;
    int lane = t & 63;
    int w = t >> 6;
    int half = lane >> 5;              // 0: batches 0-3, 1: batches 4-7
    int l32 = lane & 31;
    int j = blockIdx.x;                // 2048 blocks: xcd(3) | c0low(6) | q(2)
    int xcd = j & 7;
    int c0 = (xcd << 6) + ((j >> 3) & 63);
    int q4 = j >> 9;                   // [0,4)
    int c1base = (q4 << 7) + (w << 5); // [0,512) step 32
    int c1 = c1base + l32;
    int wa = c1 - 3, wb = c1 + 2;      // lane's bin window (unwrapped)

    char* myl = lds[w];

    float aR[4], aI[4];
#pragma unroll
    for (int b = 0; b < 4; ++b) { aR[b] = 0.0f; aI[b] = 0.0f; }

    for (int j0 = 0; j0 < JJ; ++j0) {
        int r0 = (c0 - (j0 - 2)) & (KK - 1);
        int rowbase = r0 << 9;
        int lo = c1base - 3, hi = c1base + 33;
        int nseg, ga0, gb0, ga1, gb1;
        if (lo < 0)        { ga0 = lo; gb0 = -1;  ga1 = 0;   gb1 = hi; nseg = 2; }
        else if (hi > 511) { ga0 = lo; gb0 = 511; ga1 = 512; gb1 = hi; nseg = 2; }
        else               { ga0 = lo; gb0 = hi;  ga1 = 0;   gb1 = 0;  nseg = 1; }

        for (int sgi = 0; sgi < nseg; ++sgi) {
            int ga = sgi ? ga1 : ga0;
            int gb = sgi ? gb1 : gb0;
            int pstart = offsets[rowbase + (ga & 511)];          // wave-uniform
            int pend   = offsets[rowbase + ((gb & 511) + 1)];    // wave-uniform
            int ia = max(wa, ga), ib = min(wb, gb);
            bool has = ia <= ib;
            int pA = has ? offsets[rowbase + (ia & 511)] : 0;
            int pB = has ? ((ib == gb) ? pend
                                       : offsets[rowbase + ((ib + 1) & 511)]) : 0;

            for (int pc = pstart; pc < pend; pc += 32) {
                int cnt = min(32, pend - pc);
                int sub = lane & 3;
                int prow = lane >> 2;      // [0,16)
#pragma unroll
                for (int qq = 0; qq < 2; ++qq) {
                    if (16 * qq < cnt) {
                        int pp = min(pc + prow + 16 * qq, MPTS - 1);
                        float4 v = *(const float4*)(rec + (size_t)pp * 64 + sub * 16);
                        *(float4*)(myl + (prow + 16 * qq) * 88 + sub * 16) = v;
                    }
                }
                int pLo = max(pA, pc), pHi = min(pB, pc + cnt);
                for (int p = pLo; p < pHi; ++p) {
                    const char* rp = myl + (p - pc) * 88;
                    int bin1 = *(const int*)(rp + 24);
                    int idx = (c1 - bin1 + 2) & 511;   // wrap-exact o1+2
                    bool ok = idx <= 5;
                    idx = ok ? idx : 0;
                    float w0 = (float)*(const _Float16*)(rp + j0 * 2);
                    float w1 = (float)*(const _Float16*)(rp + 12 + idx * 2);
                    float ww = ok ? w0 * w1 : 0.0f;
                    h8 yv = *(const h8*)(rp + 32 + (half << 4));
#pragma unroll
                    for (int b = 0; b < 4; ++b) {
                        aR[b] += (float)yv[2 * b]     * ww;   // v_fma_mix
                        aI[b] += (float)yv[2 * b + 1] * ww;
                    }
                }
            }
        }
    }

    float2* g2 = (float2*)grid;
    int c = (c0 << 9) + c1;
#pragma unroll
    for (int b = 0; b < 4; ++b)
        g2[((size_t)((half << 2) + b) << 18) + c] = make_float2(aR[b], aI[b]);
}

// ---------- per-wave 512-pt FFT: 8(reg) x 64(lanes via shfl), sign +i ----------
__device__ __forceinline__ void wave_fft512(float xr[8], float xi[8], int lane,
                                            const float2* __restrict__ tw)
{
    float a0r = xr[0]+xr[4], a0i = xi[0]+xi[4];
    float a4r = xr[0]-xr[4], a4i = xi[0]-xi[4];
    float a2r = xr[2]+xr[6], a2i = xi[2]+xi[6];
    float a6r = xr[2]-xr[6], a6i = xi[2]-xi[6];
    float a1r = xr[1]+xr[5], a1i = xi[1]+xi[5];
    float a5r = xr[1]-xr[5], a5i = xi[1]-xi[5];
    float a3r = xr[3]+xr[7], a3i = xi[3]+xi[7];
    float a7r = xr[3]-xr[7], a7i = xi[3]-xi[7];
    float b0r = a0r+a2r, b0i = a0i+a2i;
    float b2r = a0r-a2r, b2i = a0i-a2i;
    float b4r = a4r-a6i, b4i = a4i+a6r;    // a4 + i*a6
    float b6r = a4r+a6i, b6i = a4i-a6r;    // a4 - i*a6
    float b1r = a1r+a3r, b1i = a1i+a3i;
    float b3r = a1r-a3r, b3i = a1i-a3i;
    float b5r = a5r-a7i, b5i = a5i+a7r;
    float b7r = a5r+a7i, b7i = a5i-a7r;
    const float S2 = 0.70710678118654752f;
    float w5r = S2*(b5r-b5i), w5i = S2*(b5r+b5i);     // W8^1 * b5
    float w7r = -S2*(b7r+b7i), w7i = S2*(b7r-b7i);    // W8^3 * b7
    float y0r = b0r+b1r, y0i = b0i+b1i;
    float y4r = b0r-b1r, y4i = b0i-b1i;
    float y1r = b4r+w5r, y1i = b4i+w5i;
    float y5r = b4r-w5r, y5i = b4i-w5i;
    float y2r = b2r-b3i, y2i = b2i+b3r;    // b2 + i*b3
    float y6r = b2r+b3i, y6i = b2i-b3r;
    float y3r = b6r+w7r, y3i = b6i+w7i;
    float y7r = b6r-w7r, y7i = b6i-w7i;

    int p = __brev((unsigned)lane) >> 26;
    float2 w0v = tw[p];
    float c1 = w0v.x, s1 = w0v.y;
    float wr = c1, wi = s1, tr;
    xr[0] = y0r; xi[0] = y0i;
    xr[1] = y1r*wr - y1i*wi; xi[1] = y1i*wr + y1r*wi;
    tr = wr*c1 - wi*s1; wi = wr*s1 + wi*c1; wr = tr;
    xr[2] = y2r*wr - y2i*wi; xi[2] = y2i*wr + y2r*wi;
    tr = wr*c1 - wi*s1; wi = wr*s1 + wi*c1; wr = tr;
    xr[3] = y3r*wr - y3i*wi; xi[3] = y3i*wr + y3r*wi;
    tr = wr*c1 - wi*s1; wi = wr*s1 + wi*c1; wr = tr;
    xr[4] = y4r*wr - y4i*wi; xi[4] = y4i*wr + y4r*wi;
    tr = wr*c1 - wi*s1; wi = wr*s1 + wi*c1; wr = tr;
    xr[5] = y5r*wr - y5i*wi; xi[5] = y5i*wr + y5r*wi;
    tr = wr*c1 - wi*s1; wi = wr*s1 + wi*c1; wr = tr;
    xr[6] = y6r*wr - y6i*wi; xi[6] = y6i*wr + y6r*wi;
    tr = wr*c1 - wi*s1; wi = wr*s1 + wi*c1; wr = tr;
    xr[7] = y7r*wr - y7i*wi; xi[7] = y7i*wr + y7r*wi;

#pragma unroll
    for (int t = 0; t < 6; ++t) {
        int m = 1 << t;
        int j = lane & (m - 1);
        float wc, wsn;
        sincosf((float)M_PI * (float)j / (float)m, &wsn, &wc);
        bool hi = (lane & m) != 0;
#pragma unroll
        for (int d = 0; d < 8; ++d) {
            float pR = __shfl_xor(xr[d], m, 64);
            float pI = __shfl_xor(xi[d], m, 64);
            float bR = hi ? xr[d] : pR;
            float bI = hi ? xi[d] : pI;
            float aR = hi ? pR : xr[d];
            float aI = hi ? pI : xi[d];
            float wbR = wc * bR - wsn * bI;
            float wbI = wc * bI + wsn * bR;
            xr[d] = hi ? aR - wbR : aR + wbR;
            xi[d] = hi ? aI - wbI : aI + wbI;
        }
    }
}

// ---------- per-wave 256-pt FFT: 4(reg) x 64(lanes), sign +i ----------
// Input: reg a holds x[brev6(lane) + 64a]. Output: lane l holds X[4l + d].
__device__ __forceinline__ void wave_fft256(float xr[4], float xi[4], int lane,
                                            const float2* __restrict__ tw)
{
    // FFT4 over a (natural in/out, +i)
    float t0r = xr[0]+xr[2], t0i = xi[0]+xi[2];
    float t1r = xr[0]-xr[2], t1i = xi[0]-xi[2];
    float t2r = xr[1]+xr[3], t2i = xi[1]+xi[3];
    float t3r = xr[1]-xr[3], t3i = xi[1]-xi[3];
    float y0r = t0r+t2r, y0i = t0i+t2i;
    float y2r = t0r-t2r, y2i = t0i-t2i;
    float y1r = t1r-t3i, y1i = t1i+t3r;    // t1 + i*t3
    float y3r = t1r+t3i, y3i = t1i-t3r;    // t1 - i*t3

    // twiddle T[d] = Y[d]*w^d, w = e^{+2pi i p/256} = tw[2p]
    int p = __brev((unsigned)lane) >> 26;
    float2 wv = tw[p << 1];
    float c1 = wv.x, s1 = wv.y;
    float wr = c1, wi = s1, tr;
    xr[0] = y0r; xi[0] = y0i;
    xr[1] = y1r*wr - y1i*wi; xi[1] = y1i*wr + y1r*wi;
    tr = wr*c1 - wi*s1; wi = wr*s1 + wi*c1; wr = tr;
    xr[2] = y2r*wr - y2i*wi; xi[2] = y2i*wr + y2r*wi;
    tr = wr*c1 - wi*s1; wi = wr*s1 + wi*c1; wr = tr;
    xr[3] = y3r*wr - y3i*wi; xi[3] = y3i*wr + y3r*wi;

    // cross-lane FFT64 over p (same structure as wave_fft512)
#pragma unroll
    for (int t = 0; t < 6; ++t) {
        int m = 1 << t;
        int j = lane & (m - 1);
        float wc, wsn;
        sincosf((float)M_PI * (float)j / (float)m, &wsn, &wc);
        bool hi = (lane & m) != 0;
#pragma unroll
        for (int d = 0; d < 4; ++d) {
            float pR = __shfl_xor(xr[d], m, 64);
            float pI = __shfl_xor(xi[d], m, 64);
            float bR = hi ? xr[d] : pR;
            float bI = hi ? xi[d] : pI;
            float aR = hi ? pR : xr[d];
            float aI = hi ? pI : xi[d];
            float wbR = wc * bR - wsn * bI;
            float wbI = wc * bI + wsn * bR;
            xr[d] = hi ? aR - wbR : aR + wbR;
            xi[d] = hi ? aI - wbI : aI + wbI;
        }
    }
}

// fftA: k2-transform. 512 blocks x 8 waves; wave = row (b, k1).
// Block mapping XCD-aligned with gather's c0-band: x = blk&7 selects the
// k1 64-band so grid reads hit the XCD-local L2.
__global__ __launch_bounds__(512) void fftA(
    const float2* __restrict__ grid2, float2* __restrict__ C)
{
    __shared__ float sR[2112], sI[2112];   // 8 waves * 264, stride33 swizzle
    __shared__ float2 tw[256];
    int t = threadIdx.x;
    int lane = t & 63;
    int w = t >> 6;
    int x  = blockIdx.x & 7;                       // XCD = k1 band
    int b  = (blockIdx.x >> 3) & 7;
    int k1base = (x << 6) | (((blockIdx.x >> 6) & 7) << 3);
    int k1 = k1base + w;

    if (t < 256) {
        float ang = (float)(2.0 * M_PI / 512.0) * (float)t;
        float s, c; sincosf(ang, &s, &c);
        tw[t] = make_float2(c, s);
    }

    const float2* row = grid2 + ((size_t)b << 18) + ((size_t)k1 << 9);
    int p = __brev((unsigned)lane) >> 26;
    float xr[8], xi[8];
#pragma unroll
    for (int a = 0; a < 8; ++a) {
        float2 v = row[p + (a << 6)];
        xr[a] = v.x; xi[a] = v.y;
    }
    __syncthreads();                       // table ready

    wave_fft512(xr, xi, lane, tw);

    bool act = (lane < 16) | (lane >= 48);
    int lpp = (lane < 16) ? lane : (lane - 32);   // [0,32)
    if (act) {
#pragma unroll
        for (int d = 0; d < 8; ++d) {
            int addr = w * 264 + d * 33 + lpp;    // conflict-free swizzle
            sR[addr] = xr[d];
            sI[addr] = xi[d];
        }
    }
    __syncthreads();

#pragma unroll
    for (int pp = 0; pp < 4; ++pp) {
        int idx = pp * 512 + t;                   // [0,2048) = 256 s2 x 8 k1
        int kk = idx & 7;
        int s2 = idx >> 3;
        int v = (s2 + 128) & 255;                 // v = 8*lpp + d
        int d = v & 7;
        int lp = v >> 3;
        int addr = kk * 264 + d * 33 + lp;
        C[(((size_t)(b << 8) + s2) << 9) + k1base + kk] = make_float2(sR[addr], sI[addr]);
    }
}

// fftB v2: split-row. 512 blocks x 8 waves; wave PAIR per row (b, s2):
// even wave FFT256 of x[2n], odd wave FFT256 of x[2n+1]; odd stores
// re(O[k]*W512^k) to LDS; even combines E[k] +/- WO[k] (real part only),
// applies LDS apod, stores contiguous float4 runs, block-reduced min/max.
__global__ __launch_bounds__(512) void fftB(
    const float2* __restrict__ C, float* __restrict__ imgT, float beta2,
    float* __restrict__ pmin, float* __restrict__ pmax)
{
    __shared__ float2 tw[256];
    __shared__ float invd[256];
    __shared__ __align__(16) float wor[4][256];
    __shared__ float wmn[4], wmx[4];
    int t = threadIdx.x;
    int lane = t & 63;
    int w = t >> 6;                    // [0,8)
    int row = w >> 1;                  // [0,4)
    int odd = w & 1;
    int rowid = blockIdx.x * 4 + row;  // [0,2048) = b*256 + s2
    int b = rowid >> 8;                // uniform across block (4 | 256)
    int s2 = rowid & 255;

    if (t < 256) {
        float ang = (float)(2.0 * M_PI / 512.0) * (float)t;
        float s, c; sincosf(ang, &s, &c);
        tw[t] = make_float2(c, s);
    } else if (t < 512) {
        int i = t - 256;
        const float XF = (float)(M_PI * (double)JJ / (double)KK);
        float n = (float)(i - 128);
        float xf = XF * n;
        float arg = beta2 - xf * xf;
        float sq = sqrtf(arg);
        invd[i] = sq / sinhf(sq);      // 1/d(i-128)
    }

    const float2* rowp = C + ((size_t)rowid << 9);
    int p = __brev((unsigned)lane) >> 26;
    float xr[4], xi[4];
#pragma unroll
    for (int a = 0; a < 4; ++a) {
        float2 v = rowp[((p + (a << 6)) << 1) | odd];   // even/odd samples
        xr[a] = v.x; xi[a] = v.y;
    }
    __syncthreads();                   // tables ready

    wave_fft256(xr, xi, lane, tw);     // lane holds F[4*lane + d]

    if (odd) {
        // store re(O[k] * tw[k]), k = 4*lane+d
        float4 wo;
#pragma unroll
        for (int d = 0; d < 4; ++d) {
            int k = (lane << 2) + d;
            float2 wv = tw[k];
            ((float*)&wo)[d] = xr[d] * wv.x - xi[d] * wv.y;
        }
        *(float4*)&wor[row][lane << 2] = wo;
    }
    __syncthreads();                   // wor ready

    if (!odd) {
        const float INVK2 = 1.0f / ((float)KK * (float)KK);
        float sbase = INVK2 * invd[s2];
        float lmin = 1e30f, lmax = -1e30f;
        float4 wo = *(const float4*)&wor[row][lane << 2];
        float vals[4];
#pragma unroll
        for (int d = 0; d < 4; ++d) {
            int k = (lane << 2) + d;
            float e = xr[d];                       // re(E[k])
            float woK = ((const float*)&wo)[d];
            float xre = (k < 128) ? (e + woK) : (e - woK);
            int r = (k + 128) & 255;
            float o = xre * sbase * invd[r];
            vals[d] = o;
            lmin = fminf(lmin, o);
            lmax = fmaxf(lmax, o);
        }
        int r0run = ((lane << 2) + 128) & 255;     // 4-aligned, no wrap straddle
        *(float4*)(imgT + ((size_t)b << 16) + (s2 << 8) + r0run) =
            make_float4(vals[0], vals[1], vals[2], vals[3]);
#pragma unroll
        for (int off = 32; off >= 1; off >>= 1) {
            lmin = fminf(lmin, __shfl_xor(lmin, off, 64));
            lmax = fmaxf(lmax, __shfl_xor(lmax, off, 64));
        }
        if (lane == 0) { wmn[row] = lmin; wmx[row] = lmax; }
    }
    __syncthreads();
    if (t == 0) {
        float mn = fminf(fminf(wmn[0], wmn[1]), fminf(wmn[2], wmn[3]));
        float mx = fmaxf(fmaxf(wmx[0], wmx[1]), fmaxf(wmx[2], wmx[3]));
        pmin[blockIdx.x] = mn;
        pmax[blockIdx.x] = mx;
    }
}

// norm_t: normalize + transpose imgT[b][s2][r] -> out[b][r][s2].
__global__ __launch_bounds__(256) void norm_t(
    const float* __restrict__ imgT, const float* __restrict__ pmin,
    const float* __restrict__ pmax, float* __restrict__ out)
{
    __shared__ float tile[64][65];
    __shared__ float s_mn, s_inv;
    int b = blockIdx.x >> 4;
    int tl = blockIdx.x & 15;
    int r0 = (tl & 3) << 6;
    int s0 = (tl >> 2) << 6;
    int tr = threadIdx.x & 63;
    int ts = threadIdx.x >> 6;        // [0,4)

    if (threadIdx.x < 64) {           // fftB blocks [64b, 64b+64) = batch b
        float mn = pmin[(b << 6) + threadIdx.x];
        float mx = pmax[(b << 6) + threadIdx.x];
#pragma unroll
        for (int off = 32; off >= 1; off >>= 1) {
            mn = fminf(mn, __shfl_xor(mn, off, 64));
            mx = fmaxf(mx, __shfl_xor(mx, off, 64));
        }
        if (threadIdx.x == 0) { s_mn = mn; s_inv = 1.0f / (mx - mn); }
    }

    const float* src = imgT + ((size_t)b << 16);
#pragma unroll
    for (int q = 0; q < 16; ++q) {
        int s2 = s0 + (q << 2) + ts;
        tile[s2 - s0][tr] = src[(s2 << 8) + r0 + tr];
    }
    __syncthreads();

    float mn = s_mn, inv = s_inv;
    float* dst = out + ((size_t)b << 16);
#pragma unroll
    for (int q = 0; q < 16; ++q) {
        int r = r0 + (q << 2) + ts;
        dst[(r << 8) + s0 + tr] = (tile[tr][r - r0] - mn) * inv;
    }
}

// ---------- host ----------

static double i0_host(double x) {
    double sum = 1.0, term = 1.0;
    double q = x * x * 0.25;
    for (int k = 1; k < 80; ++k) {
        term *= q / ((double)k * (double)k);
        sum += term;
        if (term < sum * 1e-17) break;
    }
    return sum;
}

extern "C" void kernel_launch(void* const* d_in, const int* in_sizes, int n_in,
                              void* d_out, int out_size, void* d_ws, size_t ws_size,
                              hipStream_t stream)
{
    const float* y_real  = (const float*)d_in[0];
    const float* y_imag  = (const float*)d_in[1];
    const float* weights = (const float*)d_in[2];
    const float2* uv2    = (const float2*)d_in[3];
    float* out = (float*)d_out;

    char* W = (char*)d_ws;
    // Aliased live ranges (peak ~24.4 MB):
    //  W[0,16M): counts[1M]+desc[2K] (binning) -> grid (gather->fftA) -> imgT [0,2M)
    //  A=W+16M:  rec [0,6.4M) + offsets [6.4M,7.45M) (bin->gather)
    //            -> C [0,8M) (fftA->fftB); pmin/pmax at [8.4M); lut at [8.41M)
    float*    grid    = (float*)W;                         // 16 MB
    int*      counts  = (int*)W;                           // 1 MB (aliases grid)
    unsigned long long* desc = (unsigned long long*)(W + 0x100000);  // 2 KB
    float*    imgT    = (float*)W;                         // 2 MB (aliases grid)
    char*     A       = W + (size_t)16 * 1024 * 1024;
    char*     rec     = A;                                 // 6,400,000 B
    int*      offsets = (int*)(A + 6400000);               // 1,048,580 B
    float2*   C       = (float2*)A;                        // 8 MB (aliases rec)
    float*    pmin    = (float*)(A + 8400000);             // 2 KB
    float*    pmax    = (float*)(A + 8402048);             // 2 KB
    float*    lut     = (float*)(A + 8404096);             // 4 KB

    double beta_d = M_PI * sqrt(19.45);   // BETA with alpha=2
    float beta = (float)beta_d;
    float inv_i0b = (float)(1.0 / i0_host(beta_d));
    float beta2 = (float)(beta_d * beta_d);

    // one memset covers counts (1 MB) + desc (2 KB)
    hipMemsetAsync(counts, 0, NBINS * sizeof(int) + 256 * sizeof(unsigned long long),
                   stream);

    count_bins<<<(MPTS + 255) / 256, 256, 0, stream>>>(
        uv2, counts, lut, beta, inv_i0b);

    scan_k<<<256, 1024, 0, stream>>>(counts, offsets, desc);

    fill_records<<<(MPTS + 255) / 256, 256, 0, stream>>>(
        uv2, y_real, y_imag, weights, offsets, counts, rec, lut);

    gather_grid<<<2048, 256, 0, stream>>>(offsets, rec, grid);

    fftA<<<512, 512, 0, stream>>>((const float2*)grid, C);

    fftB<<<512, 512, 0, stream>>>(C, imgT, beta2, pmin, pmax);

    norm_t<<<128, 256, 0, stream>>>(imgT, pmin, pmax, out);
}

// Round 15
// 137.837 us; speedup vs baseline: 1.2295x; 1.0306x over previous
//
#include <hip/hip_runtime.h>
#include <math.h>

// Problem constants
#define NN 256
#define KK 512
#define JJ 6
#define BB 8
#define MPTS 100000
#define NBINS (KK * KK)
// K/(2*pi)
#define KF_SCALE 81.48733086305615f

typedef _Float16 h8 __attribute__((ext_vector_type(8)));
typedef _Float16 h2 __attribute__((ext_vector_type(2)));

// ---------- device helpers ----------

// Abramowitz & Stegun 9.8.1 / 9.8.2 modified Bessel I0, float
__device__ __forceinline__ float i0f_dev(float x) {
    float ax = fabsf(x);
    if (ax < 3.75f) {
        float t = x / 3.75f; t *= t;
        return 1.0f + t*(3.5156229f + t*(3.0899424f + t*(1.2067492f +
               t*(0.2659732f + t*(0.0360768f + t*0.0045813f)))));
    } else {
        float t = 3.75f / ax;
        return (expf(ax) * rsqrtf(ax)) *
               (0.39894228f + t*(0.01328592f + t*(0.00225319f + t*(-0.00157565f +
                t*(0.00916281f + t*(-0.02057706f + t*(0.02635537f +
                t*(-0.01647633f + t*0.00392377f))))))));
    }
}

__device__ __forceinline__ float kbf(float t, float beta, float inv_i0b) {
    float u = t * (1.0f / 3.0f);       // 2*t/J, J=6
    float q = fmaxf(1.0f - u * u, 0.0f);
    return i0f_dev(beta * sqrtf(q)) * inv_i0b;
}

// inclusive wave scan (64 lanes)
__device__ __forceinline__ int wave_scan(int x, int lane) {
#pragma unroll
    for (int off = 1; off < 64; off <<= 1) {
        int y = __shfl_up(x, off, 64);
        if (lane >= off) x += y;
    }
    return x;
}

// KB weight via 1024-entry LUT over t in [-3,3], linear interp (err ~4e-4)
__device__ __forceinline__ float kb_lut(const float* __restrict__ sT, float t) {
    float u = (t + 3.0f) * (1023.0f / 6.0f);
    int i = (int)u;
    i = min(i, 1022);
    float f = u - (float)i;
    float a = sT[i];
    return a + f * (sT[i + 1] - sT[i]);
}

// ---------- binning kernels ----------

// count_bins also builds the KB LUT.
__global__ __launch_bounds__(256) void count_bins(
    const float2* __restrict__ uv2, int* __restrict__ counts,
    float* __restrict__ lut, float beta, float inv_i0b)
{
    int m = blockIdx.x * 256 + threadIdx.x;
    if (m < 1024) {
        float t = -3.0f + (6.0f / 1023.0f) * (float)m;
        lut[m] = kbf(t, beta, inv_i0b);
    }
    if (m >= MPTS) return;
    float2 u = uv2[m];
    int b0 = (int)floorf(u.x * KF_SCALE) & (KK - 1);
    int b1 = (int)floorf(u.y * KF_SCALE) & (KK - 1);
    atomicAdd(&counts[(b0 << 9) | b1], 1);
}

// Single-pass decoupled-lookback exclusive scan of counts[262144] -> offsets.
__global__ __launch_bounds__(1024) void scan_k(
    const int* __restrict__ counts, int* __restrict__ offsets,
    unsigned long long* __restrict__ desc)
{
    __shared__ int part[16];
    __shared__ int s_prefix;
    int tid = threadIdx.x;
    int lane = tid & 63;
    int w = tid >> 6;                       // [0,16)
    int g = blockIdx.x * 1024 + tid;

    int v = counts[g];
    int x = wave_scan(v, lane);
    if (lane == 63) part[w] = x;
    __syncthreads();
    if (tid < 16) {
        int p = part[tid];
#pragma unroll
        for (int off = 1; off < 16; off <<= 1) {
            int y = __shfl_up(p, off, 64);
            if (tid >= off) p += y;
        }
        part[tid] = p;
    }
    __syncthreads();
    int incl = x + ((w > 0) ? part[w - 1] : 0);
    int total = part[15];                   // block aggregate

    if (tid == 0) {
        unsigned long long pack = ((unsigned long long)(unsigned)total << 2) |
                                  ((blockIdx.x == 0) ? 2ULL : 1ULL);
        atomicExch(&desc[blockIdx.x], pack);
        if (blockIdx.x == 0) s_prefix = 0;
    }

    if (blockIdx.x > 0 && w == 0) {
        int prefix = 0;
        int base = blockIdx.x - 1;
        bool done = false;
        while (!done) {
            int idx = base - lane;          // lane 0 = nearest predecessor
            unsigned long long d = 0;
            if (idx >= 0) {
                do { d = atomicAdd(&desc[idx], 0ULL); } while ((d & 3ULL) == 0ULL);
            }
            unsigned long long mask = __ballot(idx >= 0 && (d & 3ULL) == 2ULL);
            int f = (mask != 0ULL) ? (__ffsll((long long)mask) - 1) : 64;
            int contrib = (idx >= 0 && lane <= f) ? (int)(d >> 2) : 0;
#pragma unroll
            for (int off = 1; off < 64; off <<= 1)
                contrib += __shfl_xor(contrib, off, 64);
            prefix += contrib;
            base -= 64;
            done = (mask != 0ULL);
        }
        if (lane == 0) {
            s_prefix = prefix;
            atomicExch(&desc[blockIdx.x],
                       ((unsigned long long)(unsigned)(prefix + total) << 2) | 2ULL);
        }
    }
    __syncthreads();

    offsets[g] = incl - v + s_prefix;
    if (g == 0) offsets[NBINS] = MPTS;
}

// fill_records: 64B record per point, written to its CSR slot (sorted by bin).
__global__ __launch_bounds__(256) void fill_records(
    const float2* __restrict__ uv2,
    const float* __restrict__ y_real, const float* __restrict__ y_imag,
    const float* __restrict__ weights, const int* __restrict__ offsets,
    int* __restrict__ counts, char* __restrict__ rec,
    const float* __restrict__ lut)
{
    __shared__ float sT[1024];
    int tid = threadIdx.x;
#pragma unroll
    for (int q = 0; q < 4; ++q) sT[q * 256 + tid] = lut[q * 256 + tid];
    __syncthreads();

    int m = blockIdx.x * 256 + tid;
    if (m >= MPTS) return;
    float2 u = uv2[m];
    float kf0 = u.x * KF_SCALE;
    float kf1 = u.y * KF_SCALE;
    float f0 = floorf(kf0), f1 = floorf(kf1);
    float fr0 = kf0 - f0, fr1 = kf1 - f1;
    int b1c = (int)f1 & (KK - 1);
    int bin = (((int)f0 & (KK - 1)) << 9) | b1c;
    int old = atomicSub(&counts[bin], 1);
    int slot = offsets[bin] + old - 1;

    _Float16 hw[12];
#pragma unroll
    for (int j = 0; j < JJ; ++j) {
        hw[j]     = (_Float16)kb_lut(sT, (float)(j - 2) - fr0);
        hw[6 + j] = (_Float16)kb_lut(sT, (float)(j - 2) - fr1);
    }

    float4 c0v, c1v;
    _Float16* p0 = (_Float16*)&c0v;
    _Float16* p1 = (_Float16*)&c1v;
#pragma unroll
    for (int j = 0; j < 8; ++j) p0[j] = hw[j];        // w0[0..5], w1[0..1]
#pragma unroll
    for (int j = 0; j < 4; ++j) p1[j] = hw[8 + j];    // w1[2..5]
    ((int*)&c1v)[2] = b1c;
    ((int*)&c1v)[3] = 0;

    float wm = weights[m];
    h8 ha, hb;
#pragma unroll
    for (int b = 0; b < 4; ++b) {
        ha[2 * b]     = (_Float16)(y_real[b * MPTS + m] * wm);
        ha[2 * b + 1] = (_Float16)(y_imag[b * MPTS + m] * wm);
        hb[2 * b]     = (_Float16)(y_real[(b + 4) * MPTS + m] * wm);
        hb[2 * b + 1] = (_Float16)(y_imag[(b + 4) * MPTS + m] * wm);
    }

    float4* dst = (float4*)(rec + (size_t)slot * 64);
    dst[0] = c0v;
    dst[1] = c1v;
    dst[2] = *(float4*)&ha;
    dst[3] = *(float4*)&hb;
}

// ---------- gather v6: 32 cells/wave, 2 lanes/cell; f16 grid output ----------
__global__ __launch_bounds__(256) void gather_grid(
    const int* __restrict__ offsets, const char* __restrict__ rec,
    h2* __restrict__ gridh)
{
    __shared__ __align__(16) char lds[4][2816];   // 32 pts x 88B per wave
    int t = threadIdx.x;
    int lane = t & 63;
    int w = t >> 6;
    int half = lane >> 5;              // 0: batches 0-3, 1: batches 4-7
    int l32 = lane & 31;
    int j = blockIdx.x;                // 2048 blocks: xcd(3) | c0low(6) | q(2)
    int xcd = j & 7;
    int c0 = (xcd << 6) + ((j >> 3) & 63);
    int q4 = j >> 9;                   // [0,4)
    int c1base = (q4 << 7) + (w << 5); // [0,512) step 32
    int c1 = c1base + l32;
    int wa = c1 - 3, wb = c1 + 2;      // lane's bin window (unwrapped)

    char* myl = lds[w];

    float aR[4], aI[4];
#pragma unroll
    for (int b = 0; b < 4; ++b) { aR[b] = 0.0f; aI[b] = 0.0f; }

    for (int j0 = 0; j0 < JJ; ++j0) {
        int r0 = (c0 - (j0 - 2)) & (KK - 1);
        int rowbase = r0 << 9;
        int lo = c1base - 3, hi = c1base + 33;
        int nseg, ga0, gb0, ga1, gb1;
        if (lo < 0)        { ga0 = lo; gb0 = -1;  ga1 = 0;   gb1 = hi; nseg = 2; }
        else if (hi > 511) { ga0 = lo; gb0 = 511; ga1 = 512; gb1 = hi; nseg = 2; }
        else               { ga0 = lo; gb0 = hi;  ga1 = 0;   gb1 = 0;  nseg = 1; }

        for (int sgi = 0; sgi < nseg; ++sgi) {
            int ga = sgi ? ga1 : ga0;
            int gb = sgi ? gb1 : gb0;
            int pstart = offsets[rowbase + (ga & 511)];          // wave-uniform
            int pend   = offsets[rowbase + ((gb & 511) + 1)];    // wave-uniform
            int ia = max(wa, ga), ib = min(wb, gb);
            bool has = ia <= ib;
            int pA = has ? offsets[rowbase + (ia & 511)] : 0;
            int pB = has ? ((ib == gb) ? pend
                                       : offsets[rowbase + ((ib + 1) & 511)]) : 0;

            for (int pc = pstart; pc < pend; pc += 32) {
                int cnt = min(32, pend - pc);
                int sub = lane & 3;
                int prow = lane >> 2;      // [0,16)
#pragma unroll
                for (int qq = 0; qq < 2; ++qq) {
                    if (16 * qq < cnt) {
                        int pp = min(pc + prow + 16 * qq, MPTS - 1);
                        float4 v = *(const float4*)(rec + (size_t)pp * 64 + sub * 16);
                        *(float4*)(myl + (prow + 16 * qq) * 88 + sub * 16) = v;
                    }
                }
                int pLo = max(pA, pc), pHi = min(pB, pc + cnt);
                for (int p = pLo; p < pHi; ++p) {
                    const char* rp = myl + (p - pc) * 88;
                    int bin1 = *(const int*)(rp + 24);
                    int idx = (c1 - bin1 + 2) & 511;   // wrap-exact o1+2
                    bool ok = idx <= 5;
                    idx = ok ? idx : 0;
                    float w0 = (float)*(const _Float16*)(rp + j0 * 2);
                    float w1 = (float)*(const _Float16*)(rp + 12 + idx * 2);
                    float ww = ok ? w0 * w1 : 0.0f;
                    h8 yv = *(const h8*)(rp + 32 + (half << 4));
#pragma unroll
                    for (int b = 0; b < 4; ++b) {
                        aR[b] += (float)yv[2 * b]     * ww;   // v_fma_mix
                        aI[b] += (float)yv[2 * b + 1] * ww;
                    }
                }
            }
        }
    }

    int c = (c0 << 9) + c1;
#pragma unroll
    for (int b = 0; b < 4; ++b) {
        h2 v;
        v[0] = (_Float16)aR[b];
        v[1] = (_Float16)aI[b];
        gridh[((size_t)((half << 2) + b) << 18) + c] = v;
    }
}

// ---------- per-wave 512-pt FFT: 8(reg) x 64(lanes via shfl), sign +i ----------
__device__ __forceinline__ void wave_fft512(float xr[8], float xi[8], int lane,
                                            const float2* __restrict__ tw)
{
    float a0r = xr[0]+xr[4], a0i = xi[0]+xi[4];
    float a4r = xr[0]-xr[4], a4i = xi[0]-xi[4];
    float a2r = xr[2]+xr[6], a2i = xi[2]+xi[6];
    float a6r = xr[2]-xr[6], a6i = xi[2]-xi[6];
    float a1r = xr[1]+xr[5], a1i = xi[1]+xi[5];
    float a5r = xr[1]-xr[5], a5i = xi[1]-xi[5];
    float a3r = xr[3]+xr[7], a3i = xi[3]+xi[7];
    float a7r = xr[3]-xr[7], a7i = xi[3]-xi[7];
    float b0r = a0r+a2r, b0i = a0i+a2i;
    float b2r = a0r-a2r, b2i = a0i-a2i;
    float b4r = a4r-a6i, b4i = a4i+a6r;    // a4 + i*a6
    float b6r = a4r+a6i, b6i = a4i-a6r;    // a4 - i*a6
    float b1r = a1r+a3r, b1i = a1i+a3i;
    float b3r = a1r-a3r, b3i = a1i-a3i;
    float b5r = a5r-a7i, b5i = a5i+a7r;
    float b7r = a5r+a7i, b7i = a5i-a7r;
    const float S2 = 0.70710678118654752f;
    float w5r = S2*(b5r-b5i), w5i = S2*(b5r+b5i);     // W8^1 * b5
    float w7r = -S2*(b7r+b7i), w7i = S2*(b7r-b7i);    // W8^3 * b7
    float y0r = b0r+b1r, y0i = b0i+b1i;
    float y4r = b0r-b1r, y4i = b0i-b1i;
    float y1r = b4r+w5r, y1i = b4i+w5i;
    float y5r = b4r-w5r, y5i = b4i-w5i;
    float y2r = b2r-b3i, y2i = b2i+b3r;    // b2 + i*b3
    float y6r = b2r+b3i, y6i = b2i-b3r;
    float y3r = b6r+w7r, y3i = b6i+w7i;
    float y7r = b6r-w7r, y7i = b6i-w7i;

    int p = __brev((unsigned)lane) >> 26;
    float2 w0v = tw[p];
    float c1 = w0v.x, s1 = w0v.y;
    float wr = c1, wi = s1, tr;
    xr[0] = y0r; xi[0] = y0i;
    xr[1] = y1r*wr - y1i*wi; xi[1] = y1i*wr + y1r*wi;
    tr = wr*c1 - wi*s1; wi = wr*s1 + wi*c1; wr = tr;
    xr[2] = y2r*wr - y2i*wi; xi[2] = y2i*wr + y2r*wi;
    tr = wr*c1 - wi*s1; wi = wr*s1 + wi*c1; wr = tr;
    xr[3] = y3r*wr - y3i*wi; xi[3] = y3i*wr + y3r*wi;
    tr = wr*c1 - wi*s1; wi = wr*s1 + wi*c1; wr = tr;
    xr[4] = y4r*wr - y4i*wi; xi[4] = y4i*wr + y4r*wi;
    tr = wr*c1 - wi*s1; wi = wr*s1 + wi*c1; wr = tr;
    xr[5] = y5r*wr - y5i*wi; xi[5] = y5i*wr + y5r*wi;
    tr = wr*c1 - wi*s1; wi = wr*s1 + wi*c1; wr = tr;
    xr[6] = y6r*wr - y6i*wi; xi[6] = y6i*wr + y6r*wi;
    tr = wr*c1 - wi*s1; wi = wr*s1 + wi*c1; wr = tr;
    xr[7] = y7r*wr - y7i*wi; xi[7] = y7i*wr + y7r*wi;

#pragma unroll
    for (int t = 0; t < 6; ++t) {
        int m = 1 << t;
        int j = lane & (m - 1);
        float wc, wsn;
        sincosf((float)M_PI * (float)j / (float)m, &wsn, &wc);
        bool hi = (lane & m) != 0;
#pragma unroll
        for (int d = 0; d < 8; ++d) {
            float pR = __shfl_xor(xr[d], m, 64);
            float pI = __shfl_xor(xi[d], m, 64);
            float bR = hi ? xr[d] : pR;
            float bI = hi ? xi[d] : pI;
            float aR = hi ? pR : xr[d];
            float aI = hi ? pI : xi[d];
            float wbR = wc * bR - wsn * bI;
            float wbI = wc * bI + wsn * bR;
            xr[d] = hi ? aR - wbR : aR + wbR;
            xi[d] = hi ? aI - wbI : aI + wbI;
        }
    }
}

// ---------- per-wave 256-pt FFT: 4(reg) x 64(lanes), sign +i ----------
__device__ __forceinline__ void wave_fft256(float xr[4], float xi[4], int lane,
                                            const float2* __restrict__ tw)
{
    float t0r = xr[0]+xr[2], t0i = xi[0]+xi[2];
    float t1r = xr[0]-xr[2], t1i = xi[0]-xi[2];
    float t2r = xr[1]+xr[3], t2i = xi[1]+xi[3];
    float t3r = xr[1]-xr[3], t3i = xi[1]-xi[3];
    float y0r = t0r+t2r, y0i = t0i+t2i;
    float y2r = t0r-t2r, y2i = t0i-t2i;
    float y1r = t1r-t3i, y1i = t1i+t3r;    // t1 + i*t3
    float y3r = t1r+t3i, y3i = t1i-t3r;    // t1 - i*t3

    int p = __brev((unsigned)lane) >> 26;
    float2 wv = tw[p << 1];
    float c1 = wv.x, s1 = wv.y;
    float wr = c1, wi = s1, tr;
    xr[0] = y0r; xi[0] = y0i;
    xr[1] = y1r*wr - y1i*wi; xi[1] = y1i*wr + y1r*wi;
    tr = wr*c1 - wi*s1; wi = wr*s1 + wi*c1; wr = tr;
    xr[2] = y2r*wr - y2i*wi; xi[2] = y2i*wr + y2r*wi;
    tr = wr*c1 - wi*s1; wi = wr*s1 + wi*c1; wr = tr;
    xr[3] = y3r*wr - y3i*wi; xi[3] = y3i*wr + y3r*wi;

#pragma unroll
    for (int t = 0; t < 6; ++t) {
        int m = 1 << t;
        int j = lane & (m - 1);
        float wc, wsn;
        sincosf((float)M_PI * (float)j / (float)m, &wsn, &wc);
        bool hi = (lane & m) != 0;
#pragma unroll
        for (int d = 0; d < 4; ++d) {
            float pR = __shfl_xor(xr[d], m, 64);
            float pI = __shfl_xor(xi[d], m, 64);
            float bR = hi ? xr[d] : pR;
            float bI = hi ? xi[d] : pI;
            float aR = hi ? pR : xr[d];
            float aI = hi ? pI : xi[d];
            float wbR = wc * bR - wsn * bI;
            float wbI = wc * bI + wsn * bR;
            xr[d] = hi ? aR - wbR : aR + wbR;
            xi[d] = hi ? aI - wbI : aI + wbI;
        }
    }
}

// fftA: k2-transform, f16 in / f16 out. 512 blocks x 8 waves; wave = row (b,k1).
// XCD-aligned with gather's c0-band (x = blk&7 selects the k1 64-band).
__global__ __launch_bounds__(512) void fftA(
    const h2* __restrict__ gridh, h2* __restrict__ Ch)
{
    __shared__ float sR[2112], sI[2112];   // 8 waves * 264, stride33 swizzle
    __shared__ float2 tw[256];
    int t = threadIdx.x;
    int lane = t & 63;
    int w = t >> 6;
    int x  = blockIdx.x & 7;                       // XCD = k1 band
    int b  = (blockIdx.x >> 3) & 7;
    int k1base = (x << 6) | (((blockIdx.x >> 6) & 7) << 3);
    int k1 = k1base + w;

    if (t < 256) {
        float ang = (float)(2.0 * M_PI / 512.0) * (float)t;
        float s, c; sincosf(ang, &s, &c);
        tw[t] = make_float2(c, s);
    }

    const h2* row = gridh + ((size_t)b << 18) + ((size_t)k1 << 9);
    int p = __brev((unsigned)lane) >> 26;
    float xr[8], xi[8];
#pragma unroll
    for (int a = 0; a < 8; ++a) {
        h2 v = row[p + (a << 6)];
        xr[a] = (float)v[0]; xi[a] = (float)v[1];
    }
    __syncthreads();                       // table ready

    wave_fft512(xr, xi, lane, tw);

    bool act = (lane < 16) | (lane >= 48);
    int lpp = (lane < 16) ? lane : (lane - 32);   // [0,32)
    if (act) {
#pragma unroll
        for (int d = 0; d < 8; ++d) {
            int addr = w * 264 + d * 33 + lpp;    // conflict-free swizzle
            sR[addr] = xr[d];
            sI[addr] = xi[d];
        }
    }
    __syncthreads();

#pragma unroll
    for (int pp = 0; pp < 4; ++pp) {
        int idx = pp * 512 + t;                   // [0,2048) = 256 s2 x 8 k1
        int kk = idx & 7;
        int s2 = idx >> 3;
        int v = (s2 + 128) & 255;                 // v = 8*lpp + d
        int d = v & 7;
        int lp = v >> 3;
        int addr = kk * 264 + d * 33 + lp;
        h2 o;
        o[0] = (_Float16)sR[addr];
        o[1] = (_Float16)sI[addr];
        Ch[(((size_t)(b << 8) + s2) << 9) + k1base + kk] = o;
    }
}

// fftB v2: split-row, f16 input. 512 blocks x 8 waves; wave PAIR per row.
__global__ __launch_bounds__(512) void fftB(
    const h2* __restrict__ Ch, float* __restrict__ imgT, float beta2,
    float* __restrict__ pmin, float* __restrict__ pmax)
{
    __shared__ float2 tw[256];
    __shared__ float invd[256];
    __shared__ __align__(16) float wor[4][256];
    __shared__ float wmn[4], wmx[4];
    int t = threadIdx.x;
    int lane = t & 63;
    int w = t >> 6;                    // [0,8)
    int row = w >> 1;                  // [0,4)
    int odd = w & 1;
    int rowid = blockIdx.x * 4 + row;  // [0,2048) = b*256 + s2
    int b = rowid >> 8;                // uniform across block (4 | 256)
    int s2 = rowid & 255;

    if (t < 256) {
        float ang = (float)(2.0 * M_PI / 512.0) * (float)t;
        float s, c; sincosf(ang, &s, &c);
        tw[t] = make_float2(c, s);
    } else if (t < 512) {
        int i = t - 256;
        const float XF = (float)(M_PI * (double)JJ / (double)KK);
        float n = (float)(i - 128);
        float xf = XF * n;
        float arg = beta2 - xf * xf;
        float sq = sqrtf(arg);
        invd[i] = sq / sinhf(sq);      // 1/d(i-128)
    }

    const h2* rowp = Ch + ((size_t)rowid << 9);
    int p = __brev((unsigned)lane) >> 26;
    float xr[4], xi[4];
#pragma unroll
    for (int a = 0; a < 4; ++a) {
        h2 v = rowp[((p + (a << 6)) << 1) | odd];   // even/odd samples
        xr[a] = (float)v[0]; xi[a] = (float)v[1];
    }
    __syncthreads();                   // tables ready

    wave_fft256(xr, xi, lane, tw);     // lane holds F[4*lane + d]

    if (odd) {
        float4 wo;
#pragma unroll
        for (int d = 0; d < 4; ++d) {
            int k = (lane << 2) + d;
            float2 wv = tw[k];
            ((float*)&wo)[d] = xr[d] * wv.x - xi[d] * wv.y;
        }
        *(float4*)&wor[row][lane << 2] = wo;
    }
    __syncthreads();                   // wor ready

    if (!odd) {
        const float INVK2 = 1.0f / ((float)KK * (float)KK);
        float sbase = INVK2 * invd[s2];
        float lmin = 1e30f, lmax = -1e30f;
        float4 wo = *(const float4*)&wor[row][lane << 2];
        float vals[4];
#pragma unroll
        for (int d = 0; d < 4; ++d) {
            int k = (lane << 2) + d;
            float e = xr[d];                       // re(E[k])
            float woK = ((const float*)&wo)[d];
            float xre = (k < 128) ? (e + woK) : (e - woK);
            int r = (k + 128) & 255;
            float o = xre * sbase * invd[r];
            vals[d] = o;
            lmin = fminf(lmin, o);
            lmax = fmaxf(lmax, o);
        }
        int r0run = ((lane << 2) + 128) & 255;     // 4-aligned, no wrap straddle
        *(float4*)(imgT + ((size_t)b << 16) + (s2 << 8) + r0run) =
            make_float4(vals[0], vals[1], vals[2], vals[3]);
#pragma unroll
        for (int off = 32; off >= 1; off >>= 1) {
            lmin = fminf(lmin, __shfl_xor(lmin, off, 64));
            lmax = fmaxf(lmax, __shfl_xor(lmax, off, 64));
        }
        if (lane == 0) { wmn[row] = lmin; wmx[row] = lmax; }
    }
    __syncthreads();
    if (t == 0) {
        float mn = fminf(fminf(wmn[0], wmn[1]), fminf(wmn[2], wmn[3]));
        float mx = fmaxf(fmaxf(wmx[0], wmx[1]), fmaxf(wmx[2], wmx[3]));
        pmin[blockIdx.x] = mn;
        pmax[blockIdx.x] = mx;
    }
}

// norm_t: normalize + transpose imgT[b][s2][r] -> out[b][r][s2].
__global__ __launch_bounds__(256) void norm_t(
    const float* __restrict__ imgT, const float* __restrict__ pmin,
    const float* __restrict__ pmax, float* __restrict__ out)
{
    __shared__ float tile[64][65];
    __shared__ float s_mn, s_inv;
    int b = blockIdx.x >> 4;
    int tl = blockIdx.x & 15;
    int r0 = (tl & 3) << 6;
    int s0 = (tl >> 2) << 6;
    int tr = threadIdx.x & 63;
    int ts = threadIdx.x >> 6;        // [0,4)

    if (threadIdx.x < 64) {           // fftB blocks [64b, 64b+64) = batch b
        float mn = pmin[(b << 6) + threadIdx.x];
        float mx = pmax[(b << 6) + threadIdx.x];
#pragma unroll
        for (int off = 32; off >= 1; off >>= 1) {
            mn = fminf(mn, __shfl_xor(mn, off, 64));
            mx = fmaxf(mx, __shfl_xor(mx, off, 64));
        }
        if (threadIdx.x == 0) { s_mn = mn; s_inv = 1.0f / (mx - mn); }
    }

    const float* src = imgT + ((size_t)b << 16);
#pragma unroll
    for (int q = 0; q < 16; ++q) {
        int s2 = s0 + (q << 2) + ts;
        tile[s2 - s0][tr] = src[(s2 << 8) + r0 + tr];
    }
    __syncthreads();

    float mn = s_mn, inv = s_inv;
    float* dst = out + ((size_t)b << 16);
#pragma unroll
    for (int q = 0; q < 16; ++q) {
        int r = r0 + (q << 2) + ts;
        dst[(r << 8) + s0 + tr] = (tile[tr][r - r0] - mn) * inv;
    }
}

// ---------- host ----------

static double i0_host(double x) {
    double sum = 1.0, term = 1.0;
    double q = x * x * 0.25;
    for (int k = 1; k < 80; ++k) {
        term *= q / ((double)k * (double)k);
        sum += term;
        if (term < sum * 1e-17) break;
    }
    return sum;
}

extern "C" void kernel_launch(void* const* d_in, const int* in_sizes, int n_in,
                              void* d_out, int out_size, void* d_ws, size_t ws_size,
                              hipStream_t stream)
{
    const float* y_real  = (const float*)d_in[0];
    const float* y_imag  = (const float*)d_in[1];
    const float* weights = (const float*)d_in[2];
    const float2* uv2    = (const float2*)d_in[3];
    float* out = (float*)d_out;

    char* W = (char*)d_ws;
    // Aliased live ranges (peak ~24.4 MB):
    //  W[0,16M): counts[1M]+desc[2K] (binning) -> gridh [0,8M) f16 (gather->fftA)
    //            -> imgT [0,2M) (fftB->norm)
    //  A=W+16M:  rec [0,6.4M) + offsets [6.4M,7.45M) (bin->gather)
    //            -> Ch [0,4M) f16 (fftA->fftB); pmin/pmax at [8.4M); lut at [8.41M)
    h2*       gridh   = (h2*)W;                            // 8 MB (f16 pairs)
    int*      counts  = (int*)W;                           // 1 MB (aliases gridh)
    unsigned long long* desc = (unsigned long long*)(W + 0x100000);  // 2 KB
    float*    imgT    = (float*)W;                         // 2 MB (aliases gridh)
    char*     A       = W + (size_t)16 * 1024 * 1024;
    char*     rec     = A;                                 // 6,400,000 B
    int*      offsets = (int*)(A + 6400000);               // 1,048,580 B
    h2*       Ch      = (h2*)A;                            // 4 MB (aliases rec)
    float*    pmin    = (float*)(A + 8400000);             // 2 KB
    float*    pmax    = (float*)(A + 8402048);             // 2 KB
    float*    lut     = (float*)(A + 8404096);             // 4 KB

    double beta_d = M_PI * sqrt(19.45);   // BETA with alpha=2
    float beta = (float)beta_d;
    float inv_i0b = (float)(1.0 / i0_host(beta_d));
    float beta2 = (float)(beta_d * beta_d);

    // one memset covers counts (1 MB) + desc (2 KB)
    hipMemsetAsync(counts, 0, NBINS * sizeof(int) + 256 * sizeof(unsigned long long),
                   stream);

    count_bins<<<(MPTS + 255) / 256, 256, 0, stream>>>(
        uv2, counts, lut, beta, inv_i0b);

    scan_k<<<256, 1024, 0, stream>>>(counts, offsets, desc);

    fill_records<<<(MPTS + 255) / 256, 256, 0, stream>>>(
        uv2, y_real, y_imag, weights, offsets, counts, rec, lut);

    gather_grid<<<2048, 256, 0, stream>>>(offsets, rec, gridh);

    fftA<<<512, 512, 0, stream>>>(gridh, Ch);

    fftB<<<512, 512, 0, stream>>>(Ch, imgT, beta2, pmin, pmax);

    norm_t<<<128, 256, 0, stream>>>(imgT, pmin, pmax, out);
}